// Round 1
// baseline (3574.046 us; speedup 1.0000x reference)
//
#include <hip/hip_runtime.h>

typedef __bf16 bf16;
typedef __bf16 bf16x8 __attribute__((ext_vector_type(8)));
typedef float f32x4 __attribute__((ext_vector_type(4)));
typedef short short4v __attribute__((ext_vector_type(4)));

__device__ __forceinline__ short f2bs(float x) {
  bf16 hv = (bf16)x;
  return __builtin_bit_cast(short, hv);
}

// ---------------------------------------------------------------------------
// Embedding: h[m][d] = emb[x[m]][d]*32 + PE(s,d)
// ---------------------------------------------------------------------------
__global__ __launch_bounds__(256) void embed_k(const int* __restrict__ x,
    const float* __restrict__ emb, float* __restrict__ h)
{
  const int m = blockIdx.x, t = threadIdx.x;
  const int s = m & 1023;
  const int tok = x[m];
  const int d0 = t * 4;
  float4 e = *(const float4*)(emb + (size_t)tok * 1024 + d0);
  const float* ep = &e.x;
  float r[4];
#pragma unroll
  for (int j = 0; j < 4; ++j) {
    int d = d0 + j;
    float freq = expf((float)(d & ~1) * (-9.2103403719761836f / 1024.f));
    float ang = (float)s * freq;
    float pe = (d & 1) ? cosf(ang) : sinf(ang);
    r[j] = ep[j] * 32.f + pe;
  }
  *(float4*)(h + (size_t)m * 1024 + d0) = make_float4(r[0], r[1], r[2], r[3]);
}

// ---------------------------------------------------------------------------
// LayerNorm (fp32 in, bf16 out), one block per row of 1024
// ---------------------------------------------------------------------------
__global__ __launch_bounds__(256) void ln_k(const float* __restrict__ h,
    const float* __restrict__ g, const float* __restrict__ b,
    bf16* __restrict__ out)
{
  const int row = blockIdx.x, t = threadIdx.x;
  const float* hr = h + (size_t)row * 1024;
  float4 x = *(const float4*)(hr + t * 4);
  float s  = x.x + x.y + x.z + x.w;
  float ss = x.x * x.x + x.y * x.y + x.z * x.z + x.w * x.w;
#pragma unroll
  for (int off = 32; off >= 1; off >>= 1) {
    s  += __shfl_down(s, off);
    ss += __shfl_down(ss, off);
  }
  __shared__ float sb[4], ssb[4];
  if ((t & 63) == 0) { sb[t >> 6] = s; ssb[t >> 6] = ss; }
  __syncthreads();
  s  = sb[0] + sb[1] + sb[2] + sb[3];
  ss = ssb[0] + ssb[1] + ssb[2] + ssb[3];
  const float mean = s * (1.f / 1024.f);
  const float var  = ss * (1.f / 1024.f) - mean * mean;
  const float rstd = rsqrtf(var + 1e-5f);
  const float* xp = &x.x;
#pragma unroll
  for (int j = 0; j < 4; ++j) {
    int d = t * 4 + j;
    out[(size_t)row * 1024 + d] = (bf16)((xp[j] - mean) * rstd * g[d] + b[d]);
  }
}

// ---------------------------------------------------------------------------
// GEMM: C(MxN) = A(bf16 MxK) * W(f32 KxN), 128x128 tile, BK=32, 4 waves.
// MODE 0: C=bf16       1: C=bf16 relu(acc+bias)   2: Hacc += acc
// MODE 3: Hacc += acc+bias    4: C=f32 acc+bias   5: QKV (3 weights, bf16 out)
// ---------------------------------------------------------------------------
template<int MODE>
__global__ __launch_bounds__(256) void gemm_k(
    const bf16* __restrict__ A, const float* __restrict__ W0,
    const float* __restrict__ W1p, const float* __restrict__ W2p,
    const float* __restrict__ bias, void* __restrict__ Cout,
    float* __restrict__ Hacc, int M, int N, int K)
{
  __shared__ __align__(16) bf16 As[128][40];
  __shared__ __align__(16) bf16 Bs[128][40];   // Bs[n][k] (transposed)
  const int tid = threadIdx.x;
  const int lane = tid & 63;
  const int wid = tid >> 6;
  const int wm = wid >> 1, wn = wid & 1;
  const int m0 = blockIdx.y * 128;
  const int n0 = blockIdx.x * 128;

  const float* W = W0;
  int ldw = N, wn0 = n0;
  if (MODE == 5) {
    int sel = n0 >> 10;
    W = (sel == 0) ? W0 : ((sel == 1) ? W1p : W2p);
    ldw = 1024; wn0 = n0 & 1023;
  }

  const int kb2 = (tid & 15) * 2;      // B-staging: k pair
  const int n8  = (tid >> 4) * 8;      // B-staging: 8 n cols

  f32x4 acc[4][4];
#pragma unroll
  for (int i = 0; i < 4; ++i)
#pragma unroll
    for (int j = 0; j < 4; ++j) acc[i][j] = (f32x4){0.f, 0.f, 0.f, 0.f};

  const int qr = lane & 15, grp = lane >> 4;

  for (int kt = 0; kt < K; kt += 32) {
    // stage A (128x32 bf16): 2 groups of 8 bf16 per thread
#pragma unroll
    for (int gi = 0; gi < 2; ++gi) {
      int g = tid + gi * 256;
      int row = g >> 2, q4 = g & 3;
      *(bf16x8*)(&As[row][q4 * 8]) =
          *(const bf16x8*)(A + (size_t)(m0 + row) * K + kt + q4 * 8);
    }
    // stage B transposed: thread loads rows (kt+kb2, kt+kb2+1), 8 cols, packs pairs
    {
      const float* wr  = W + (size_t)(kt + kb2) * ldw + wn0 + n8;
      const float* wr2 = wr + ldw;
      float4 x0 = *(const float4*)wr,  x1 = *(const float4*)(wr + 4);
      float4 y0 = *(const float4*)wr2, y1 = *(const float4*)(wr2 + 4);
      float fa[8] = {x0.x, x0.y, x0.z, x0.w, x1.x, x1.y, x1.z, x1.w};
      float fb[8] = {y0.x, y0.y, y0.z, y0.w, y1.x, y1.y, y1.z, y1.w};
#pragma unroll
      for (int i = 0; i < 8; ++i) {
        union { unsigned int u; bf16 hh[2]; } p;
        p.hh[0] = (bf16)fa[i];
        p.hh[1] = (bf16)fb[i];
        *(unsigned int*)(&Bs[n8 + i][kb2]) = p.u;
      }
    }
    __syncthreads();
    bf16x8 af[4], bfr[4];
#pragma unroll
    for (int mi = 0; mi < 4; ++mi)
      af[mi] = *(const bf16x8*)(&As[wm * 64 + mi * 16 + qr][grp * 8]);
#pragma unroll
    for (int ni = 0; ni < 4; ++ni)
      bfr[ni] = *(const bf16x8*)(&Bs[wn * 64 + ni * 16 + qr][grp * 8]);
#pragma unroll
    for (int mi = 0; mi < 4; ++mi)
#pragma unroll
      for (int ni = 0; ni < 4; ++ni)
        acc[mi][ni] = __builtin_amdgcn_mfma_f32_16x16x32_bf16(
            af[mi], bfr[ni], acc[mi][ni], 0, 0, 0);
    __syncthreads();
  }

  // epilogue
#pragma unroll
  for (int ni = 0; ni < 4; ++ni) {
    const int coln = wn * 64 + ni * 16 + qr;   // within 128 tile
    const int colg = n0 + coln;                // global logical col
    float bv = 0.f;
    if (MODE == 1 || MODE == 3 || MODE == 4) bv = bias[colg];
#pragma unroll
    for (int mi = 0; mi < 4; ++mi) {
#pragma unroll
      for (int r = 0; r < 4; ++r) {
        const int rowg = m0 + wm * 64 + mi * 16 + grp * 4 + r;
        float v = acc[mi][ni][r];
        if (MODE == 0) {
          ((bf16*)Cout)[(size_t)rowg * N + colg] = (bf16)v;
        } else if (MODE == 1) {
          v += bv; v = v > 0.f ? v : 0.f;
          ((bf16*)Cout)[(size_t)rowg * N + colg] = (bf16)v;
        } else if (MODE == 2) {
          Hacc[(size_t)rowg * N + colg] += v;
        } else if (MODE == 3) {
          Hacc[(size_t)rowg * N + colg] += v + bv;
        } else if (MODE == 4) {
          ((float*)Cout)[(size_t)rowg * N + colg] = v + bv;
        } else { // MODE 5: QKV
          int sel = n0 >> 10;
          bf16* cb = (bf16*)Cout + (size_t)sel * M * 1024;
          cb[(size_t)rowg * 1024 + (wn0 + coln)] = (bf16)v;
        }
      }
    }
  }
}

// ---------------------------------------------------------------------------
// Flash attention: 1 wave per (b, h, 16-q-row tile). Online softmax.
// S^T = mfma(K, Q) so each lane owns (kv=g*4+r, q=lane&15); P^T feeds the
// PV mfma (16x16x16bf16_1k) B-operand directly; O^T accumulates in C-layout.
// ---------------------------------------------------------------------------
__global__ __launch_bounds__(64) void attn_k(const bf16* __restrict__ qm,
    const bf16* __restrict__ km, const bf16* __restrict__ vm,
    bf16* __restrict__ om)
{
  const int lane = threadIdx.x;
  const int qr = lane & 15, g = lane >> 4;
  const int qt = blockIdx.x & 63;
  const int hh = (blockIdx.x >> 6) & 15;
  const int bb = blockIdx.x >> 10;
  const size_t rowb = (size_t)bb * 1024;
  const int hb = hh * 64;

  const bf16* qp = qm + (rowb + qt * 16 + qr) * 1024 + hb + g * 8;
  const bf16x8 qf0 = *(const bf16x8*)qp;
  const bf16x8 qf1 = *(const bf16x8*)(qp + 32);

  float m_run = -1e30f, l_run = 0.f;
  f32x4 oacc[4];
#pragma unroll
  for (int dt = 0; dt < 4; ++dt) oacc[dt] = (f32x4){0.f, 0.f, 0.f, 0.f};

  const int qglob = qt * 16 + qr;

  for (int kvt = 0; kvt <= qt; ++kvt) {
    const bf16* kp = km + (rowb + kvt * 16 + qr) * 1024 + hb + g * 8;
    bf16x8 kf0 = *(const bf16x8*)kp;
    bf16x8 kf1 = *(const bf16x8*)(kp + 32);
    f32x4 st = (f32x4){0.f, 0.f, 0.f, 0.f};
    st = __builtin_amdgcn_mfma_f32_16x16x32_bf16(kf0, qf0, st, 0, 0, 0);
    st = __builtin_amdgcn_mfma_f32_16x16x32_bf16(kf1, qf1, st, 0, 0, 0);

    float sc[4];
#pragma unroll
    for (int r = 0; r < 4; ++r) {
      int kvg = kvt * 16 + g * 4 + r;
      sc[r] = (kvg <= qglob) ? st[r] * 0.125f : -1e30f;
    }
    float mloc = fmaxf(fmaxf(sc[0], sc[1]), fmaxf(sc[2], sc[3]));
    mloc = fmaxf(mloc, __shfl_xor(mloc, 16));
    mloc = fmaxf(mloc, __shfl_xor(mloc, 32));
    float m_new = fmaxf(m_run, mloc);
    float alpha = __expf(m_run - m_new);
    float p[4], ps = 0.f;
#pragma unroll
    for (int r = 0; r < 4; ++r) { p[r] = __expf(sc[r] - m_new); ps += p[r]; }
    ps += __shfl_xor(ps, 16);
    ps += __shfl_xor(ps, 32);
    l_run = l_run * alpha + ps;
    m_run = m_new;

    short4v pf;
#pragma unroll
    for (int r = 0; r < 4; ++r) pf[r] = f2bs(p[r]);
#pragma unroll
    for (int dt = 0; dt < 4; ++dt) oacc[dt] *= alpha;

    const bf16* vb = vm + (rowb + kvt * 16) * 1024 + hb;
#pragma unroll
    for (int dt = 0; dt < 4; ++dt) {
      short4v vf;
#pragma unroll
      for (int j = 0; j < 4; ++j)
        vf[j] = __builtin_bit_cast(short, vb[(size_t)(g * 4 + j) * 1024 + dt * 16 + qr]);
      oacc[dt] = __builtin_amdgcn_mfma_f32_16x16x16bf16_1k(vf, pf, oacc[dt], 0, 0, 0);
    }
  }

  const float inv = 1.f / l_run;
  bf16* op = om + (rowb + qt * 16 + qr) * 1024 + hb;
#pragma unroll
  for (int dt = 0; dt < 4; ++dt)
#pragma unroll
    for (int r = 0; r < 4; ++r)
      op[dt * 16 + g * 4 + r] = (bf16)(oacc[dt][r] * inv);
}

// ---------------------------------------------------------------------------
extern "C" void kernel_launch(void* const* d_in, const int* in_sizes, int n_in,
                              void* d_out, int out_size, void* d_ws, size_t ws_size,
                              hipStream_t stream)
{
  (void)in_sizes; (void)n_in; (void)out_size; (void)ws_size;
  const int*   x     = (const int*)d_in[0];
  // d_in[1] = mask (causal tril) — applied analytically in attn_k
  const float* emb   = (const float*)d_in[2];
  const float* Wq    = (const float*)d_in[3];
  const float* Wk    = (const float*)d_in[4];
  const float* Wv    = (const float*)d_in[5];
  const float* Wo    = (const float*)d_in[6];
  const float* ln1g  = (const float*)d_in[7];
  const float* ln1b  = (const float*)d_in[8];
  const float* ln2g  = (const float*)d_in[9];
  const float* ln2b  = (const float*)d_in[10];
  const float* W1    = (const float*)d_in[11];
  const float* b1    = (const float*)d_in[12];
  const float* W2    = (const float*)d_in[13];
  const float* b2    = (const float*)d_in[14];
  const float* lnfg  = (const float*)d_in[15];
  const float* lnfb  = (const float*)d_in[16];
  const float* projW = (const float*)d_in[17];
  const float* projb = (const float*)d_in[18];

  char* ws = (char*)d_ws;
  float* h   = (float*)ws;                           // 8 MB fp32 residual
  bf16*  ain = (bf16*)(ws + (8u  << 20));            // 4 MB
  bf16*  qkv = (bf16*)(ws + (12u << 20));            // 12 MB (q,k,v)
  bf16*  ob  = (bf16*)(ws + (24u << 20));            // 4 MB
  bf16*  mid = (bf16*)(ws + (28u << 20));            // 16 MB
  bf16*  qb = qkv;
  bf16*  kb = qkv + (size_t)2048 * 1024;
  bf16*  vb = kb  + (size_t)2048 * 1024;

  embed_k<<<dim3(2048), 256, 0, stream>>>(x, emb, h);
  for (int i = 0; i < 8; ++i) {
    size_t wo = (size_t)i * 1024 * 1024;
    ln_k<<<dim3(2048), 256, 0, stream>>>(h, ln1g + i * 1024, ln1b + i * 1024, ain);
    gemm_k<5><<<dim3(24, 16), 256, 0, stream>>>(ain, Wq + wo, Wk + wo, Wv + wo,
                                                nullptr, qkv, nullptr, 2048, 3072, 1024);
    attn_k<<<dim3(2048), 64, 0, stream>>>(qb, kb, vb, ob);
    gemm_k<2><<<dim3(8, 16), 256, 0, stream>>>(ob, Wo + wo, nullptr, nullptr,
                                               nullptr, nullptr, h, 2048, 1024, 1024);
    ln_k<<<dim3(2048), 256, 0, stream>>>(h, ln2g + i * 1024, ln2b + i * 1024, ain);
    gemm_k<1><<<dim3(32, 16), 256, 0, stream>>>(ain, W1 + (size_t)i * 1024 * 4096,
                                                nullptr, nullptr, b1 + i * 4096,
                                                mid, nullptr, 2048, 4096, 1024);
    gemm_k<3><<<dim3(8, 16), 256, 0, stream>>>(mid, W2 + (size_t)i * 4096 * 1024,
                                               nullptr, nullptr, b2 + i * 1024,
                                               nullptr, h, 2048, 1024, 4096);
  }
  ln_k<<<dim3(2048), 256, 0, stream>>>(h, lnfg, lnfb, ain);
  gemm_k<4><<<dim3(250, 16), 256, 0, stream>>>(ain, projW, nullptr, nullptr,
                                               projb, d_out, nullptr, 2048, 32000, 1024);
}

// Round 2
// 2735.388 us; speedup vs baseline: 1.3066x; 1.3066x over previous
//
#include <hip/hip_runtime.h>

typedef __bf16 bf16;
typedef __bf16 bf16x4 __attribute__((ext_vector_type(4)));
typedef __bf16 bf16x8 __attribute__((ext_vector_type(8)));
typedef float f32x4 __attribute__((ext_vector_type(4)));
typedef short short4v __attribute__((ext_vector_type(4)));

__device__ __forceinline__ short f2bs(float x) {
  bf16 hv = (bf16)x;
  return __builtin_bit_cast(short, hv);
}

__device__ __forceinline__ void gl_lds16(const void* g, void* l) {
  __builtin_amdgcn_global_load_lds(
      (const __attribute__((address_space(1))) unsigned int*)g,
      (__attribute__((address_space(3))) unsigned int*)l, 16, 0, 0);
}

// ---------------------------------------------------------------------------
// Weight transpose+convert: in fp32 [K][N] (layer-strided) -> out bf16 [N][K]
// ---------------------------------------------------------------------------
__global__ __launch_bounds__(256) void wt_k(const float* __restrict__ in,
    bf16* __restrict__ out, int K, int N, long in_ls, long out_ls)
{
  __shared__ float t[32][33];
  const int z = blockIdx.z;
  const float* ip = in + (size_t)z * in_ls;
  bf16* op = out + (size_t)z * out_ls;
  const int n0 = blockIdx.x * 32, k0 = blockIdx.y * 32;
  const int tid = threadIdx.x;
  {
    const int kr = tid >> 3, nc = (tid & 7) * 4;
    float4 v = *(const float4*)(ip + (size_t)(k0 + kr) * N + n0 + nc);
    t[kr][nc] = v.x; t[kr][nc + 1] = v.y; t[kr][nc + 2] = v.z; t[kr][nc + 3] = v.w;
  }
  __syncthreads();
  {
    const int nr = tid >> 3, kc = (tid & 7) * 4;
    bf16x4 o;
#pragma unroll
    for (int j = 0; j < 4; ++j) o[j] = (bf16)t[kc + j][nr];
    *(bf16x4*)(op + (size_t)(n0 + nr) * K + k0 + kc) = o;
  }
}

// ---------------------------------------------------------------------------
// Embedding: h[m][d] = emb[x[m]][d]*32 + PE(s,d)
// ---------------------------------------------------------------------------
__global__ __launch_bounds__(256) void embed_k(const int* __restrict__ x,
    const float* __restrict__ emb, float* __restrict__ h)
{
  const int m = blockIdx.x, t = threadIdx.x;
  const int s = m & 1023;
  const int tok = x[m];
  const int d0 = t * 4;
  float4 e = *(const float4*)(emb + (size_t)tok * 1024 + d0);
  const float* ep = &e.x;
  float r[4];
#pragma unroll
  for (int j = 0; j < 4; ++j) {
    int d = d0 + j;
    float freq = expf((float)(d & ~1) * (-9.2103403719761836f / 1024.f));
    float ang = (float)s * freq;
    float pe = (d & 1) ? cosf(ang) : sinf(ang);
    r[j] = ep[j] * 32.f + pe;
  }
  *(float4*)(h + (size_t)m * 1024 + d0) = make_float4(r[0], r[1], r[2], r[3]);
}

// ---------------------------------------------------------------------------
// LayerNorm (fp32 in, bf16 out), one block per row of 1024
// ---------------------------------------------------------------------------
__global__ __launch_bounds__(256) void ln_k(const float* __restrict__ h,
    const float* __restrict__ g, const float* __restrict__ b,
    bf16* __restrict__ out)
{
  const int row = blockIdx.x, t = threadIdx.x;
  const float* hr = h + (size_t)row * 1024;
  float4 x = *(const float4*)(hr + t * 4);
  float s  = x.x + x.y + x.z + x.w;
  float ss = x.x * x.x + x.y * x.y + x.z * x.z + x.w * x.w;
#pragma unroll
  for (int off = 32; off >= 1; off >>= 1) {
    s  += __shfl_down(s, off);
    ss += __shfl_down(ss, off);
  }
  __shared__ float sb[4], ssb[4];
  if ((t & 63) == 0) { sb[t >> 6] = s; ssb[t >> 6] = ss; }
  __syncthreads();
  s  = sb[0] + sb[1] + sb[2] + sb[3];
  ss = ssb[0] + ssb[1] + ssb[2] + ssb[3];
  const float mean = s * (1.f / 1024.f);
  const float var  = ss * (1.f / 1024.f) - mean * mean;
  const float rstd = rsqrtf(var + 1e-5f);
  const float* xp = &x.x;
#pragma unroll
  for (int j = 0; j < 4; ++j) {
    int d = t * 4 + j;
    out[(size_t)row * 1024 + d] = (bf16)((xp[j] - mean) * rstd * g[d] + b[d]);
  }
}

// ---------------------------------------------------------------------------
// GEMM v2: C(MxN) = A(bf16 [M][K]) * Bt(bf16 [N][K])^T
// 128x128 tile, BK=64, 4 waves, global_load_lds staging, XOR-swizzled LDS.
// MODE 1: C=bf16 relu(acc+bias)    MODE 2: Hacc += acc
// MODE 3: Hacc += acc+bias         MODE 4: C=f32 acc+bias
// MODE 5: QKV split: cols [0,1024)->q, [1024,2048)->k, [2048,3072)->Vt (transposed)
// Grid: flat, M/128 row tiles fastest (weight-panel sharing), XCD-swizzled.
// ---------------------------------------------------------------------------
template<int MODE>
__global__ __launch_bounds__(256) void gemm2_k(
    const bf16* __restrict__ A, const bf16* __restrict__ Bt,
    const float* __restrict__ bias, void* __restrict__ Cout,
    float* __restrict__ Hacc, bf16* __restrict__ Vt,
    int M, int N, int K)
{
  __shared__ __align__(16) bf16 As[128 * 64];
  __shared__ __align__(16) bf16 Bs[128 * 64];

  // bijective XCD swizzle on flat block id
  const int nwg = gridDim.x;
  const int orig = blockIdx.x;
  const int q8 = nwg >> 3, r8 = nwg & 7;
  const int xcd = orig & 7, loc = orig >> 3;
  const int wg = (xcd < r8 ? xcd * (q8 + 1) : r8 * (q8 + 1) + (xcd - r8) * q8) + loc;
  const int rowt = wg & 15;          // M/128 == 16 always here
  const int colt = wg >> 4;
  const int m0 = rowt * 128;
  const int n0 = colt * 128;

  const int tid = threadIdx.x;
  const int lane = tid & 63;
  const int wbase = tid & ~63;
  const int wid = tid >> 6;
  const int wm = wid >> 1, wn = wid & 1;
  const int qr = lane & 15, grp = lane >> 4;

  f32x4 acc[4][4];
#pragma unroll
  for (int i = 0; i < 4; ++i)
#pragma unroll
    for (int j = 0; j < 4; ++j) acc[i][j] = (f32x4){0.f, 0.f, 0.f, 0.f};

  for (int kt = 0; kt < K; kt += 64) {
    // stage A and B tiles (128x64 bf16 each) via global_load_lds, 16B/lane.
    // LDS is linear [row][64]; global source col is inverse-XOR-swizzled.
#pragma unroll
    for (int it = 0; it < 4; ++it) {
      const int idx = it * 256 + tid;
      const int row = idx >> 3, c = idx & 7;
      const int bo = (c * 16) ^ ((row & 7) << 4);
      const char* ga = (const char*)(A + (size_t)(m0 + row) * K + kt) + bo;
      gl_lds16(ga, (char*)As + (size_t)(it * 256 + wbase) * 16);
    }
#pragma unroll
    for (int it = 0; it < 4; ++it) {
      const int idx = it * 256 + tid;
      const int row = idx >> 3, c = idx & 7;
      const int bo = (c * 16) ^ ((row & 7) << 4);
      const char* ga = (const char*)(Bt + (size_t)(n0 + row) * K + kt) + bo;
      gl_lds16(ga, (char*)Bs + (size_t)(it * 256 + wbase) * 16);
    }
    __syncthreads();
#pragma unroll
    for (int ks = 0; ks < 2; ++ks) {
      bf16x8 af[4], bfr[4];
#pragma unroll
      for (int mi = 0; mi < 4; ++mi) {
        const int arow = wm * 64 + mi * 16 + qr;
        const int ab = arow * 128 + ((grp * 16 + ks * 64) ^ ((arow & 7) << 4));
        af[mi] = *(const bf16x8*)((const char*)As + ab);
      }
#pragma unroll
      for (int ni = 0; ni < 4; ++ni) {
        const int brow = wn * 64 + ni * 16 + qr;
        const int bb = brow * 128 + ((grp * 16 + ks * 64) ^ ((brow & 7) << 4));
        bfr[ni] = *(const bf16x8*)((const char*)Bs + bb);
      }
#pragma unroll
      for (int mi = 0; mi < 4; ++mi)
#pragma unroll
        for (int ni = 0; ni < 4; ++ni)
          acc[mi][ni] = __builtin_amdgcn_mfma_f32_16x16x32_bf16(
              af[mi], bfr[ni], acc[mi][ni], 0, 0, 0);
    }
    __syncthreads();
  }

  // epilogue
  const int sel = (MODE == 5) ? (n0 >> 10) : 0;
#pragma unroll
  for (int ni = 0; ni < 4; ++ni) {
    const int coln = wn * 64 + ni * 16 + qr;
    const int colg = n0 + coln;
    float bv = 0.f;
    if (MODE == 1 || MODE == 3 || MODE == 4) bv = bias[colg];
#pragma unroll
    for (int mi = 0; mi < 4; ++mi) {
      const int rowg0 = m0 + wm * 64 + mi * 16 + grp * 4;
      if (MODE == 5 && sel == 2) {
        // V^T write: Vt[b][colg&1023][s], 4 consecutive s per thread
        const int b = rowg0 >> 10, s = rowg0 & 1023;
        bf16x4 pv;
#pragma unroll
        for (int r = 0; r < 4; ++r) pv[r] = (bf16)acc[mi][ni][r];
        *(bf16x4*)(Vt + (size_t)b * 1024 * 1024 + (size_t)(colg & 1023) * 1024 + s) = pv;
      } else {
#pragma unroll
        for (int r = 0; r < 4; ++r) {
          const int rowg = rowg0 + r;
          float v = acc[mi][ni][r];
          if (MODE == 1) {
            v += bv; v = v > 0.f ? v : 0.f;
            ((bf16*)Cout)[(size_t)rowg * N + colg] = (bf16)v;
          } else if (MODE == 2) {
            Hacc[(size_t)rowg * N + colg] += v;
          } else if (MODE == 3) {
            Hacc[(size_t)rowg * N + colg] += v + bv;
          } else if (MODE == 4) {
            ((float*)Cout)[(size_t)rowg * N + colg] = v + bv;
          } else { // MODE 5, sel 0/1 -> q/k buffers (contiguous)
            bf16* cb = (bf16*)Cout + (size_t)sel * 2048 * 1024;
            cb[(size_t)rowg * 1024 + (colg & 1023)] = (bf16)v;
          }
        }
      }
    }
  }
}

// ---------------------------------------------------------------------------
// Flash attention: 1 wave per (b, h, 16-q-row tile). Online softmax.
// S^T = mfma(K, Q); P^T feeds PV (16x16x16bf16_1k) B-operand; V read from Vt.
// ---------------------------------------------------------------------------
__global__ __launch_bounds__(64) void attn_k(const bf16* __restrict__ qm,
    const bf16* __restrict__ km, const bf16* __restrict__ vt,
    bf16* __restrict__ om)
{
  const int lane = threadIdx.x;
  const int qr = lane & 15, g = lane >> 4;
  const int qt = blockIdx.x & 63;
  const int hh = (blockIdx.x >> 6) & 15;
  const int bb = blockIdx.x >> 10;
  const size_t rowb = (size_t)bb * 1024;
  const int hb = hh * 64;

  const bf16* qp = qm + (rowb + qt * 16 + qr) * 1024 + hb + g * 8;
  const bf16x8 qf0 = *(const bf16x8*)qp;
  const bf16x8 qf1 = *(const bf16x8*)(qp + 32);

  float m_run = -1e30f, l_run = 0.f;
  f32x4 oacc[4];
#pragma unroll
  for (int dt = 0; dt < 4; ++dt) oacc[dt] = (f32x4){0.f, 0.f, 0.f, 0.f};

  const int qglob = qt * 16 + qr;
  const bf16* vtb = vt + (size_t)bb * 1024 * 1024;

  for (int kvt = 0; kvt <= qt; ++kvt) {
    const bf16* kp = km + (rowb + kvt * 16 + qr) * 1024 + hb + g * 8;
    bf16x8 kf0 = *(const bf16x8*)kp;
    bf16x8 kf1 = *(const bf16x8*)(kp + 32);
    f32x4 st = (f32x4){0.f, 0.f, 0.f, 0.f};
    st = __builtin_amdgcn_mfma_f32_16x16x32_bf16(kf0, qf0, st, 0, 0, 0);
    st = __builtin_amdgcn_mfma_f32_16x16x32_bf16(kf1, qf1, st, 0, 0, 0);

    float sc[4];
#pragma unroll
    for (int r = 0; r < 4; ++r) {
      int kvg = kvt * 16 + g * 4 + r;
      sc[r] = (kvg <= qglob) ? st[r] * 0.125f : -1e30f;
    }
    float mloc = fmaxf(fmaxf(sc[0], sc[1]), fmaxf(sc[2], sc[3]));
    mloc = fmaxf(mloc, __shfl_xor(mloc, 16));
    mloc = fmaxf(mloc, __shfl_xor(mloc, 32));
    float m_new = fmaxf(m_run, mloc);
    float alpha = __expf(m_run - m_new);
    float p[4], ps = 0.f;
#pragma unroll
    for (int r = 0; r < 4; ++r) { p[r] = __expf(sc[r] - m_new); ps += p[r]; }
    ps += __shfl_xor(ps, 16);
    ps += __shfl_xor(ps, 32);
    l_run = l_run * alpha + ps;
    m_run = m_new;

    short4v pf;
#pragma unroll
    for (int r = 0; r < 4; ++r) pf[r] = f2bs(p[r]);
#pragma unroll
    for (int dt = 0; dt < 4; ++dt) oacc[dt] *= alpha;

#pragma unroll
    for (int dt = 0; dt < 4; ++dt) {
      short4v vf = __builtin_bit_cast(short4v,
          *(const bf16x4*)(vtb + (size_t)(hb + dt * 16 + qr) * 1024 + kvt * 16 + g * 4));
      oacc[dt] = __builtin_amdgcn_mfma_f32_16x16x16bf16_1k(vf, pf, oacc[dt], 0, 0, 0);
    }
  }

  const float inv = 1.f / l_run;
  bf16* op = om + (rowb + qt * 16 + qr) * 1024 + hb;
#pragma unroll
  for (int dt = 0; dt < 4; ++dt)
#pragma unroll
    for (int r = 0; r < 4; ++r)
      op[dt * 16 + g * 4 + r] = (bf16)(oacc[dt][r] * inv);
}

// ---------------------------------------------------------------------------
extern "C" void kernel_launch(void* const* d_in, const int* in_sizes, int n_in,
                              void* d_out, int out_size, void* d_ws, size_t ws_size,
                              hipStream_t stream)
{
  (void)in_sizes; (void)n_in; (void)out_size; (void)ws_size;
  const int*   x     = (const int*)d_in[0];
  const float* emb   = (const float*)d_in[2];
  const float* Wq    = (const float*)d_in[3];
  const float* Wk    = (const float*)d_in[4];
  const float* Wv    = (const float*)d_in[5];
  const float* Wo    = (const float*)d_in[6];
  const float* ln1g  = (const float*)d_in[7];
  const float* ln1b  = (const float*)d_in[8];
  const float* ln2g  = (const float*)d_in[9];
  const float* ln2b  = (const float*)d_in[10];
  const float* W1    = (const float*)d_in[11];
  const float* b1    = (const float*)d_in[12];
  const float* W2    = (const float*)d_in[13];
  const float* b2    = (const float*)d_in[14];
  const float* lnfg  = (const float*)d_in[15];
  const float* lnfb  = (const float*)d_in[16];
  const float* projW = (const float*)d_in[17];
  const float* projb = (const float*)d_in[18];

  char* ws = (char*)d_ws;
  const size_t MB = 1u << 20;
  float* h    = (float*)(ws + 0);            // 8 MB
  bf16*  ain  = (bf16*)(ws + 8 * MB);        // 4 MB
  bf16*  qb   = (bf16*)(ws + 12 * MB);       // 4 MB
  bf16*  kb   = (bf16*)(ws + 16 * MB);       // 4 MB
  bf16*  vtb  = (bf16*)(ws + 20 * MB);       // 4 MB (V^T)
  bf16*  ob   = (bf16*)(ws + 24 * MB);       // 4 MB
  bf16*  mid  = (bf16*)(ws + 28 * MB);       // 16 MB
  bf16*  Bqkv = (bf16*)(ws + 44 * MB);       // 48 MB: [8][3][1024][1024]
  bf16*  Bo   = (bf16*)(ws + 92 * MB);       // 16 MB: [8][1024][1024]
  bf16*  B1t  = (bf16*)(ws + 108 * MB);      // 64 MB: [8][4096][1024]
  bf16*  B2t  = (bf16*)(ws + 172 * MB);      // 64 MB: [8][1024][4096]
  bf16*  Bprj = (bf16*)(ws + 236 * MB);      // 65.5 MB: [32000][1024]

  const long M1 = 1024 * 1024, M3 = 3 * M1, M4 = 4 * M1;

  // weight pre-pass: fp32 [K][N] -> bf16 [N][K]
  wt_k<<<dim3(32, 32, 8),   256, 0, stream>>>(Wq, Bqkv,          1024, 1024, M1, M3);
  wt_k<<<dim3(32, 32, 8),   256, 0, stream>>>(Wk, Bqkv + M1,     1024, 1024, M1, M3);
  wt_k<<<dim3(32, 32, 8),   256, 0, stream>>>(Wv, Bqkv + 2 * M1, 1024, 1024, M1, M3);
  wt_k<<<dim3(32, 32, 8),   256, 0, stream>>>(Wo, Bo,            1024, 1024, M1, M1);
  wt_k<<<dim3(128, 32, 8),  256, 0, stream>>>(W1, B1t,           1024, 4096, M4, M4);
  wt_k<<<dim3(32, 128, 8),  256, 0, stream>>>(W2, B2t,           4096, 1024, M4, M4);
  wt_k<<<dim3(1000, 32, 1), 256, 0, stream>>>(projW, Bprj,       1024, 32000, 0, 0);

  embed_k<<<dim3(2048), 256, 0, stream>>>(x, emb, h);
  for (int i = 0; i < 8; ++i) {
    ln_k<<<dim3(2048), 256, 0, stream>>>(h, ln1g + i * 1024, ln1b + i * 1024, ain);
    gemm2_k<5><<<dim3(384), 256, 0, stream>>>(ain, Bqkv + i * M3, nullptr,
                                              qb, nullptr, vtb, 2048, 3072, 1024);
    attn_k<<<dim3(2048), 64, 0, stream>>>(qb, kb, vtb, ob);
    gemm2_k<2><<<dim3(128), 256, 0, stream>>>(ob, Bo + i * M1, nullptr,
                                              nullptr, h, nullptr, 2048, 1024, 1024);
    ln_k<<<dim3(2048), 256, 0, stream>>>(h, ln2g + i * 1024, ln2b + i * 1024, ain);
    gemm2_k<1><<<dim3(512), 256, 0, stream>>>(ain, B1t + i * M4, b1 + i * 4096,
                                              mid, nullptr, nullptr, 2048, 4096, 1024);
    gemm2_k<3><<<dim3(128), 256, 0, stream>>>(mid, B2t + i * M4, b2 + i * 1024,
                                              nullptr, h, nullptr, 2048, 1024, 4096);
  }
  ln_k<<<dim3(2048), 256, 0, stream>>>(h, lnfg, lnfb, ain);
  gemm2_k<4><<<dim3(4000), 256, 0, stream>>>(ain, Bprj, projb,
                                             d_out, nullptr, nullptr, 2048, 32000, 1024);
}

// Round 3
// 2197.252 us; speedup vs baseline: 1.6266x; 1.2449x over previous
//
#include <hip/hip_runtime.h>

typedef __bf16 bf16;
typedef __bf16 bf16x4 __attribute__((ext_vector_type(4)));
typedef __bf16 bf16x8 __attribute__((ext_vector_type(8)));
typedef float f32x4 __attribute__((ext_vector_type(4)));
typedef short short4v __attribute__((ext_vector_type(4)));

__device__ __forceinline__ short f2bs(float x) {
  bf16 hv = (bf16)x;
  return __builtin_bit_cast(short, hv);
}

__device__ __forceinline__ void gl_lds16(const void* g, void* l) {
  __builtin_amdgcn_global_load_lds(
      (const __attribute__((address_space(1))) unsigned int*)g,
      (__attribute__((address_space(3))) unsigned int*)l, 16, 0, 0);
}

// ---------------------------------------------------------------------------
// Weight transpose+convert v2: fp32 [K][N] -> bf16 [N][K]; 64k x 32n tile,
// 16B bf16x8 stores.
// ---------------------------------------------------------------------------
__global__ __launch_bounds__(256) void wt_k(const float* __restrict__ in,
    bf16* __restrict__ out, int K, int N, long in_ls, long out_ls)
{
  __shared__ float t[64][33];
  const int z = blockIdx.z;
  const float* ip = in + (size_t)z * in_ls;
  bf16* op = out + (size_t)z * out_ls;
  const int n0 = blockIdx.x * 32, k0 = blockIdx.y * 64;
  const int tid = threadIdx.x;
  const int kr = tid >> 3, nc = (tid & 7) * 4;
#pragma unroll
  for (int hh = 0; hh < 2; ++hh) {
    float4 v = *(const float4*)(ip + (size_t)(k0 + kr + hh * 32) * N + n0 + nc);
    t[kr + hh * 32][nc]     = v.x;
    t[kr + hh * 32][nc + 1] = v.y;
    t[kr + hh * 32][nc + 2] = v.z;
    t[kr + hh * 32][nc + 3] = v.w;
  }
  __syncthreads();
  const int nr = tid >> 3, kc = (tid & 7) * 8;
  bf16x8 o;
#pragma unroll
  for (int j = 0; j < 8; ++j) o[j] = (bf16)t[kc + j][nr];
  *(bf16x8*)(op + (size_t)(n0 + nr) * K + k0 + kc) = o;
}

// ---------------------------------------------------------------------------
// Embedding: h[m][d] = emb[x[m]][d]*32 + PE(s,d)
// ---------------------------------------------------------------------------
__global__ __launch_bounds__(256) void embed_k(const int* __restrict__ x,
    const float* __restrict__ emb, float* __restrict__ h)
{
  const int m = blockIdx.x, t = threadIdx.x;
  const int s = m & 1023;
  const int tok = x[m];
  const int d0 = t * 4;
  float4 e = *(const float4*)(emb + (size_t)tok * 1024 + d0);
  const float* ep = &e.x;
  float r[4];
#pragma unroll
  for (int j = 0; j < 4; ++j) {
    int d = d0 + j;
    float freq = expf((float)(d & ~1) * (-9.2103403719761836f / 1024.f));
    float ang = (float)s * freq;
    float pe = (d & 1) ? cosf(ang) : sinf(ang);
    r[j] = ep[j] * 32.f + pe;
  }
  *(float4*)(h + (size_t)m * 1024 + d0) = make_float4(r[0], r[1], r[2], r[3]);
}

// ---------------------------------------------------------------------------
// LayerNorm (fp32 in, bf16 out), one block per row of 1024
// ---------------------------------------------------------------------------
__global__ __launch_bounds__(256) void ln_k(const float* __restrict__ h,
    const float* __restrict__ g, const float* __restrict__ b,
    bf16* __restrict__ out)
{
  const int row = blockIdx.x, t = threadIdx.x;
  const float* hr = h + (size_t)row * 1024;
  float4 x = *(const float4*)(hr + t * 4);
  float s  = x.x + x.y + x.z + x.w;
  float ss = x.x * x.x + x.y * x.y + x.z * x.z + x.w * x.w;
#pragma unroll
  for (int off = 32; off >= 1; off >>= 1) {
    s  += __shfl_down(s, off);
    ss += __shfl_down(ss, off);
  }
  __shared__ float sb[4], ssb[4];
  if ((t & 63) == 0) { sb[t >> 6] = s; ssb[t >> 6] = ss; }
  __syncthreads();
  s  = sb[0] + sb[1] + sb[2] + sb[3];
  ss = ssb[0] + ssb[1] + ssb[2] + ssb[3];
  const float mean = s * (1.f / 1024.f);
  const float var  = ss * (1.f / 1024.f) - mean * mean;
  const float rstd = rsqrtf(var + 1e-5f);
  const float* xp = &x.x;
#pragma unroll
  for (int j = 0; j < 4; ++j) {
    int d = t * 4 + j;
    out[(size_t)row * 1024 + d] = (bf16)((xp[j] - mean) * rstd * g[d] + b[d]);
  }
}

// ---------------------------------------------------------------------------
// GEMM v3: C(MxN) = A(bf16 [M][K]) * Bt(bf16 [N][K])^T
// 128x128 tile, BK=64, 4 waves; double-buffered LDS, 2-phase pipeline:
//   prologue stage(0); loop { stage(t+1); ds_read+MFMA(t); vmcnt(0); barrier }
// MODE 1: C=bf16 relu(acc+bias)    MODE 2: Hacc += acc (atomic if NSPLIT>1)
// MODE 3: Hacc += acc+bias (atomic if NSPLIT>1, bias on split 0)
// MODE 4: C=f32 acc+bias
// MODE 5: QKV split: cols [0,1024)->q, [1024,2048)->k, [2048,3072)->Vt^T
// ---------------------------------------------------------------------------
template<int MODE, int NSPLIT>
__global__ __launch_bounds__(256) void gemm3_k(
    const bf16* __restrict__ A, const bf16* __restrict__ Bt,
    const float* __restrict__ bias, void* __restrict__ Cout,
    float* __restrict__ Hacc, bf16* __restrict__ Vt,
    int M, int N, int K)
{
  __shared__ __align__(16) bf16 As[2][128 * 64];
  __shared__ __align__(16) bf16 Bs[2][128 * 64];

  // bijective XCD swizzle on flat block id
  const int nwg = gridDim.x;
  const int orig = blockIdx.x;
  const int q8 = nwg >> 3, r8 = nwg & 7;
  const int xcd = orig & 7, loc = orig >> 3;
  const int wg = (xcd < r8 ? xcd * (q8 + 1) : r8 * (q8 + 1) + (xcd - r8) * q8) + loc;
  const int nrowt = M >> 7;
  const int ntiles = nrowt * (N >> 7);
  const int split = (NSPLIT > 1) ? (wg / ntiles) : 0;
  const int tile  = (NSPLIT > 1) ? (wg % ntiles) : wg;
  const int rowt = tile & (nrowt - 1);
  const int colt = tile / nrowt;
  const int m0 = rowt * 128;
  const int n0 = colt * 128;
  const int Ks = K / NSPLIT;
  const int k_begin = split * Ks;
  const int nt = Ks >> 6;

  const int tid = threadIdx.x;
  const int lane = tid & 63;
  const int wbase = tid & ~63;
  const int wid = tid >> 6;
  const int wm = wid >> 1, wn = wid & 1;
  const int qr = lane & 15, grp = lane >> 4;

  f32x4 acc[4][4];
#pragma unroll
  for (int i = 0; i < 4; ++i)
#pragma unroll
    for (int j = 0; j < 4; ++j) acc[i][j] = (f32x4){0.f, 0.f, 0.f, 0.f};

  auto stage = [&](int bufi, int kt) {
#pragma unroll
    for (int it = 0; it < 4; ++it) {
      const int idx = it * 256 + tid;
      const int row = idx >> 3, c = idx & 7;
      const int bo = (c * 16) ^ ((row & 7) << 4);
      gl_lds16((const char*)(A + (size_t)(m0 + row) * K + kt) + bo,
               (char*)&As[bufi][0] + (size_t)(it * 256 + wbase) * 16);
    }
#pragma unroll
    for (int it = 0; it < 4; ++it) {
      const int idx = it * 256 + tid;
      const int row = idx >> 3, c = idx & 7;
      const int bo = (c * 16) ^ ((row & 7) << 4);
      gl_lds16((const char*)(Bt + (size_t)(n0 + row) * K + kt) + bo,
               (char*)&Bs[bufi][0] + (size_t)(it * 256 + wbase) * 16);
    }
  };

  stage(0, k_begin);
  asm volatile("s_waitcnt vmcnt(0)" ::: "memory");
  __builtin_amdgcn_s_barrier();

  for (int t = 0; t < nt; ++t) {
    const int cur = t & 1;
    if (t + 1 < nt) stage(cur ^ 1, k_begin + (t + 1) * 64);
#pragma unroll
    for (int ks = 0; ks < 2; ++ks) {
      bf16x8 af[4], bfr[4];
#pragma unroll
      for (int mi = 0; mi < 4; ++mi) {
        const int arow = wm * 64 + mi * 16 + qr;
        const int ab = arow * 128 + ((grp * 16 + ks * 64) ^ ((arow & 7) << 4));
        af[mi] = *(const bf16x8*)((const char*)&As[cur][0] + ab);
      }
#pragma unroll
      for (int ni = 0; ni < 4; ++ni) {
        const int brow = wn * 64 + ni * 16 + qr;
        const int bb = brow * 128 + ((grp * 16 + ks * 64) ^ ((brow & 7) << 4));
        bfr[ni] = *(const bf16x8*)((const char*)&Bs[cur][0] + bb);
      }
#pragma unroll
      for (int mi = 0; mi < 4; ++mi)
#pragma unroll
        for (int ni = 0; ni < 4; ++ni)
          acc[mi][ni] = __builtin_amdgcn_mfma_f32_16x16x32_bf16(
              af[mi], bfr[ni], acc[mi][ni], 0, 0, 0);
    }
    asm volatile("s_waitcnt vmcnt(0)" ::: "memory");
    __builtin_amdgcn_s_barrier();
  }

  // epilogue
  const int sel = (MODE == 5) ? (n0 >> 10) : 0;
#pragma unroll
  for (int ni = 0; ni < 4; ++ni) {
    const int coln = wn * 64 + ni * 16 + qr;
    const int colg = n0 + coln;
    float bv = 0.f;
    if (MODE == 1 || MODE == 4) bv = bias[colg];
    if (MODE == 3 && split == 0) bv = bias[colg];
#pragma unroll
    for (int mi = 0; mi < 4; ++mi) {
      const int rowg0 = m0 + wm * 64 + mi * 16 + grp * 4;
      if (MODE == 5 && sel == 2) {
        // V^T write: Vt[b][colg&1023][s], 4 consecutive s per thread
        const int b = rowg0 >> 10, s = rowg0 & 1023;
        bf16x4 pv;
#pragma unroll
        for (int r = 0; r < 4; ++r) pv[r] = (bf16)acc[mi][ni][r];
        *(bf16x4*)(Vt + (size_t)b * 1024 * 1024 + (size_t)(colg & 1023) * 1024 + s) = pv;
      } else {
#pragma unroll
        for (int r = 0; r < 4; ++r) {
          const int rowg = rowg0 + r;
          float v = acc[mi][ni][r];
          if (MODE == 1) {
            v += bv; v = v > 0.f ? v : 0.f;
            ((bf16*)Cout)[(size_t)rowg * N + colg] = (bf16)v;
          } else if (MODE == 2) {
            if (NSPLIT > 1) atomicAdd(&Hacc[(size_t)rowg * N + colg], v);
            else            Hacc[(size_t)rowg * N + colg] += v;
          } else if (MODE == 3) {
            if (NSPLIT > 1) atomicAdd(&Hacc[(size_t)rowg * N + colg], v + bv);
            else            Hacc[(size_t)rowg * N + colg] += v + bv;
          } else if (MODE == 4) {
            ((float*)Cout)[(size_t)rowg * N + colg] = v + bv;
          } else { // MODE 5, sel 0/1 -> q/k buffers
            bf16* cb = (bf16*)Cout + (size_t)sel * 2048 * 1024;
            cb[(size_t)rowg * 1024 + (colg & 1023)] = (bf16)v;
          }
        }
      }
    }
  }
}

// ---------------------------------------------------------------------------
// Flash attention: 1 wave per (b, h, 16-q-row tile). Online softmax.
// S^T = mfma(K, Q); P^T feeds PV (16x16x16bf16_1k) B-operand; V read from Vt.
// ---------------------------------------------------------------------------
__global__ __launch_bounds__(64) void attn_k(const bf16* __restrict__ qm,
    const bf16* __restrict__ km, const bf16* __restrict__ vt,
    bf16* __restrict__ om)
{
  const int lane = threadIdx.x;
  const int qr = lane & 15, g = lane >> 4;
  const int qt = blockIdx.x & 63;
  const int hh = (blockIdx.x >> 6) & 15;
  const int bb = blockIdx.x >> 10;
  const size_t rowb = (size_t)bb * 1024;
  const int hb = hh * 64;

  const bf16* qp = qm + (rowb + qt * 16 + qr) * 1024 + hb + g * 8;
  const bf16x8 qf0 = *(const bf16x8*)qp;
  const bf16x8 qf1 = *(const bf16x8*)(qp + 32);

  float m_run = -1e30f, l_run = 0.f;
  f32x4 oacc[4];
#pragma unroll
  for (int dt = 0; dt < 4; ++dt) oacc[dt] = (f32x4){0.f, 0.f, 0.f, 0.f};

  const int qglob = qt * 16 + qr;
  const bf16* vtb = vt + (size_t)bb * 1024 * 1024;

  for (int kvt = 0; kvt <= qt; ++kvt) {
    const bf16* kp = km + (rowb + kvt * 16 + qr) * 1024 + hb + g * 8;
    bf16x8 kf0 = *(const bf16x8*)kp;
    bf16x8 kf1 = *(const bf16x8*)(kp + 32);
    f32x4 st = (f32x4){0.f, 0.f, 0.f, 0.f};
    st = __builtin_amdgcn_mfma_f32_16x16x32_bf16(kf0, qf0, st, 0, 0, 0);
    st = __builtin_amdgcn_mfma_f32_16x16x32_bf16(kf1, qf1, st, 0, 0, 0);

    float sc[4];
#pragma unroll
    for (int r = 0; r < 4; ++r) {
      int kvg = kvt * 16 + g * 4 + r;
      sc[r] = (kvg <= qglob) ? st[r] * 0.125f : -1e30f;
    }
    float mloc = fmaxf(fmaxf(sc[0], sc[1]), fmaxf(sc[2], sc[3]));
    mloc = fmaxf(mloc, __shfl_xor(mloc, 16));
    mloc = fmaxf(mloc, __shfl_xor(mloc, 32));
    float m_new = fmaxf(m_run, mloc);
    float alpha = __expf(m_run - m_new);
    float p[4], ps = 0.f;
#pragma unroll
    for (int r = 0; r < 4; ++r) { p[r] = __expf(sc[r] - m_new); ps += p[r]; }
    ps += __shfl_xor(ps, 16);
    ps += __shfl_xor(ps, 32);
    l_run = l_run * alpha + ps;
    m_run = m_new;

    short4v pf;
#pragma unroll
    for (int r = 0; r < 4; ++r) pf[r] = f2bs(p[r]);
#pragma unroll
    for (int dt = 0; dt < 4; ++dt) oacc[dt] *= alpha;

#pragma unroll
    for (int dt = 0; dt < 4; ++dt) {
      short4v vf = __builtin_bit_cast(short4v,
          *(const bf16x4*)(vtb + (size_t)(hb + dt * 16 + qr) * 1024 + kvt * 16 + g * 4));
      oacc[dt] = __builtin_amdgcn_mfma_f32_16x16x16bf16_1k(vf, pf, oacc[dt], 0, 0, 0);
    }
  }

  const float inv = 1.f / l_run;
  bf16* op = om + (rowb + qt * 16 + qr) * 1024 + hb;
#pragma unroll
  for (int dt = 0; dt < 4; ++dt)
#pragma unroll
    for (int r = 0; r < 4; ++r)
      op[dt * 16 + g * 4 + r] = (bf16)(oacc[dt][r] * inv);
}

// ---------------------------------------------------------------------------
extern "C" void kernel_launch(void* const* d_in, const int* in_sizes, int n_in,
                              void* d_out, int out_size, void* d_ws, size_t ws_size,
                              hipStream_t stream)
{
  (void)in_sizes; (void)n_in; (void)out_size; (void)ws_size;
  const int*   x     = (const int*)d_in[0];
  const float* emb   = (const float*)d_in[2];
  const float* Wq    = (const float*)d_in[3];
  const float* Wk    = (const float*)d_in[4];
  const float* Wv    = (const float*)d_in[5];
  const float* Wo    = (const float*)d_in[6];
  const float* ln1g  = (const float*)d_in[7];
  const float* ln1b  = (const float*)d_in[8];
  const float* ln2g  = (const float*)d_in[9];
  const float* ln2b  = (const float*)d_in[10];
  const float* W1    = (const float*)d_in[11];
  const float* b1    = (const float*)d_in[12];
  const float* W2    = (const float*)d_in[13];
  const float* b2    = (const float*)d_in[14];
  const float* lnfg  = (const float*)d_in[15];
  const float* lnfb  = (const float*)d_in[16];
  const float* projW = (const float*)d_in[17];
  const float* projb = (const float*)d_in[18];

  char* ws = (char*)d_ws;
  const size_t MB = 1u << 20;
  float* h    = (float*)(ws + 0);            // 8 MB
  bf16*  ain  = (bf16*)(ws + 8 * MB);        // 4 MB
  bf16*  qb   = (bf16*)(ws + 12 * MB);       // 4 MB
  bf16*  kb   = (bf16*)(ws + 16 * MB);       // 4 MB
  bf16*  vtb  = (bf16*)(ws + 20 * MB);       // 4 MB (V^T)
  bf16*  ob   = (bf16*)(ws + 24 * MB);       // 4 MB
  bf16*  mid  = (bf16*)(ws + 28 * MB);       // 16 MB
  bf16*  Bqkv = (bf16*)(ws + 44 * MB);       // 48 MB: [8][3][1024][1024]
  bf16*  Bo   = (bf16*)(ws + 92 * MB);       // 16 MB: [8][1024][1024]
  bf16*  B1t  = (bf16*)(ws + 108 * MB);      // 64 MB: [8][4096][1024]
  bf16*  B2t  = (bf16*)(ws + 172 * MB);      // 64 MB: [8][1024][4096]
  bf16*  Bprj = (bf16*)(ws + 236 * MB);      // 65.5 MB: [32000][1024]

  const long M1 = 1024 * 1024, M3 = 3 * M1, M4 = 4 * M1;

  // weight pre-pass: fp32 [K][N] -> bf16 [N][K]
  wt_k<<<dim3(32, 16, 8),   256, 0, stream>>>(Wq, Bqkv,          1024, 1024, M1, M3);
  wt_k<<<dim3(32, 16, 8),   256, 0, stream>>>(Wk, Bqkv + M1,     1024, 1024, M1, M3);
  wt_k<<<dim3(32, 16, 8),   256, 0, stream>>>(Wv, Bqkv + 2 * M1, 1024, 1024, M1, M3);
  wt_k<<<dim3(32, 16, 8),   256, 0, stream>>>(Wo, Bo,            1024, 1024, M1, M1);
  wt_k<<<dim3(128, 16, 8),  256, 0, stream>>>(W1, B1t,           1024, 4096, M4, M4);
  wt_k<<<dim3(32, 64, 8),   256, 0, stream>>>(W2, B2t,           4096, 1024, M4, M4);
  wt_k<<<dim3(1000, 16, 1), 256, 0, stream>>>(projW, Bprj,       1024, 32000, 0, 0);

  embed_k<<<dim3(2048), 256, 0, stream>>>(x, emb, h);
  for (int i = 0; i < 8; ++i) {
    ln_k<<<dim3(2048), 256, 0, stream>>>(h, ln1g + i * 1024, ln1b + i * 1024, ain);
    gemm3_k<5,1><<<dim3(384), 256, 0, stream>>>(ain, Bqkv + i * M3, nullptr,
                                                qb, nullptr, vtb, 2048, 3072, 1024);
    attn_k<<<dim3(2048), 64, 0, stream>>>(qb, kb, vtb, ob);
    gemm3_k<2,2><<<dim3(256), 256, 0, stream>>>(ob, Bo + i * M1, nullptr,
                                                nullptr, h, nullptr, 2048, 1024, 1024);
    ln_k<<<dim3(2048), 256, 0, stream>>>(h, ln2g + i * 1024, ln2b + i * 1024, ain);
    gemm3_k<1,1><<<dim3(512), 256, 0, stream>>>(ain, B1t + i * M4, b1 + i * 4096,
                                                mid, nullptr, nullptr, 2048, 4096, 1024);
    gemm3_k<3,2><<<dim3(256), 256, 0, stream>>>(mid, B2t + i * M4, b2 + i * 1024,
                                                nullptr, h, nullptr, 2048, 1024, 4096);
  }
  ln_k<<<dim3(2048), 256, 0, stream>>>(h, lnfg, lnfb, ain);
  gemm3_k<4,1><<<dim3(4000), 256, 0, stream>>>(ain, Bprj, projb,
                                               d_out, nullptr, nullptr, 2048, 32000, 1024);
}

// Round 4
// 2169.707 us; speedup vs baseline: 1.6472x; 1.0127x over previous
//
#include <hip/hip_runtime.h>

typedef __bf16 bf16;
typedef __bf16 bf16x4 __attribute__((ext_vector_type(4)));
typedef __bf16 bf16x8 __attribute__((ext_vector_type(8)));
typedef float f32x4 __attribute__((ext_vector_type(4)));
typedef short short4v __attribute__((ext_vector_type(4)));

__device__ __forceinline__ short f2bs(float x) {
  bf16 hv = (bf16)x;
  return __builtin_bit_cast(short, hv);
}

__device__ __forceinline__ void gl_lds16(const void* g, void* l) {
  __builtin_amdgcn_global_load_lds(
      (const __attribute__((address_space(1))) unsigned int*)g,
      (__attribute__((address_space(3))) unsigned int*)l, 16, 0, 0);
}

// ---------------------------------------------------------------------------
// Weight transpose+convert: fp32 [K][N] -> bf16 [N][K]; 64k x 32n tile.
// ---------------------------------------------------------------------------
__global__ __launch_bounds__(256) void wt_k(const float* __restrict__ in,
    bf16* __restrict__ out, int K, int N, long in_ls, long out_ls)
{
  __shared__ float t[64][33];
  const int z = blockIdx.z;
  const float* ip = in + (size_t)z * in_ls;
  bf16* op = out + (size_t)z * out_ls;
  const int n0 = blockIdx.x * 32, k0 = blockIdx.y * 64;
  const int tid = threadIdx.x;
  const int kr = tid >> 3, nc = (tid & 7) * 4;
#pragma unroll
  for (int hh = 0; hh < 2; ++hh) {
    float4 v = *(const float4*)(ip + (size_t)(k0 + kr + hh * 32) * N + n0 + nc);
    t[kr + hh * 32][nc]     = v.x;
    t[kr + hh * 32][nc + 1] = v.y;
    t[kr + hh * 32][nc + 2] = v.z;
    t[kr + hh * 32][nc + 3] = v.w;
  }
  __syncthreads();
  const int nr = tid >> 3, kc = (tid & 7) * 8;
  bf16x8 o;
#pragma unroll
  for (int j = 0; j < 8; ++j) o[j] = (bf16)t[kc + j][nr];
  *(bf16x8*)(op + (size_t)(n0 + nr) * K + k0 + kc) = o;
}

// ---------------------------------------------------------------------------
// Embedding: h[m][d] = emb[x[m]][d]*32 + PE(s,d)
// ---------------------------------------------------------------------------
__global__ __launch_bounds__(256) void embed_k(const int* __restrict__ x,
    const float* __restrict__ emb, float* __restrict__ h)
{
  const int m = blockIdx.x, t = threadIdx.x;
  const int s = m & 1023;
  const int tok = x[m];
  const int d0 = t * 4;
  float4 e = *(const float4*)(emb + (size_t)tok * 1024 + d0);
  const float* ep = &e.x;
  float r[4];
#pragma unroll
  for (int j = 0; j < 4; ++j) {
    int d = d0 + j;
    float freq = expf((float)(d & ~1) * (-9.2103403719761836f / 1024.f));
    float ang = (float)s * freq;
    float pe = (d & 1) ? cosf(ang) : sinf(ang);
    r[j] = ep[j] * 32.f + pe;
  }
  *(float4*)(h + (size_t)m * 1024 + d0) = make_float4(r[0], r[1], r[2], r[3]);
}

// ---------------------------------------------------------------------------
// LayerNorm (fp32 in, bf16 out), one block per row of 1024
// ---------------------------------------------------------------------------
__global__ __launch_bounds__(256) void ln_k(const float* __restrict__ h,
    const float* __restrict__ g, const float* __restrict__ b,
    bf16* __restrict__ out)
{
  const int row = blockIdx.x, t = threadIdx.x;
  const float* hr = h + (size_t)row * 1024;
  float4 x = *(const float4*)(hr + t * 4);
  float s  = x.x + x.y + x.z + x.w;
  float ss = x.x * x.x + x.y * x.y + x.z * x.z + x.w * x.w;
#pragma unroll
  for (int off = 32; off >= 1; off >>= 1) {
    s  += __shfl_down(s, off);
    ss += __shfl_down(ss, off);
  }
  __shared__ float sb[4], ssb[4];
  if ((t & 63) == 0) { sb[t >> 6] = s; ssb[t >> 6] = ss; }
  __syncthreads();
  s  = sb[0] + sb[1] + sb[2] + sb[3];
  ss = ssb[0] + ssb[1] + ssb[2] + ssb[3];
  const float mean = s * (1.f / 1024.f);
  const float var  = ss * (1.f / 1024.f) - mean * mean;
  const float rstd = rsqrtf(var + 1e-5f);
  const float* xp = &x.x;
#pragma unroll
  for (int j = 0; j < 4; ++j) {
    int d = t * 4 + j;
    out[(size_t)row * 1024 + d] = (bf16)((xp[j] - mean) * rstd * g[d] + b[d]);
  }
}

// ---------------------------------------------------------------------------
// GEMM 256x256 (proj): C(f32) = A(bf16 [M][K]) * Bt(bf16 [N][K])^T + bias
// BK=64, 8 waves (2Mx4N), per-wave 128x64 out, dbuf LDS 128KB,
// stage(t+1) split A/B interleaved between the two ks MFMA phases.
// ---------------------------------------------------------------------------
__global__ __launch_bounds__(512, 2) void gemm256_k(
    const bf16* __restrict__ A, const bf16* __restrict__ Bt,
    const float* __restrict__ bias, float* __restrict__ C,
    int M, int N, int K)
{
  __shared__ __align__(16) bf16 As[2][256 * 64];
  __shared__ __align__(16) bf16 Bs[2][256 * 64];

  const int nwg = gridDim.x;
  const int orig = blockIdx.x;
  const int q8 = nwg >> 3, r8 = nwg & 7;
  const int xcd = orig & 7, loc = orig >> 3;
  const int wg = (xcd < r8 ? xcd * (q8 + 1) : r8 * (q8 + 1) + (xcd - r8) * q8) + loc;
  const int nrowt = M >> 8;
  const int rowt = wg & (nrowt - 1);
  const int colt = wg / nrowt;
  const int m0 = rowt * 256;
  const int n0 = colt * 256;
  const int nt = K >> 6;

  const int tid = threadIdx.x;
  const int lane = tid & 63;
  const int wbase = tid & ~63;
  const int wid = tid >> 6;
  const int wm = wid >> 2, wn = wid & 3;
  const int qr = lane & 15, grp = lane >> 4;

  f32x4 acc[8][4];
#pragma unroll
  for (int i = 0; i < 8; ++i)
#pragma unroll
    for (int j = 0; j < 4; ++j) acc[i][j] = (f32x4){0.f, 0.f, 0.f, 0.f};

  auto stageA = [&](int bufi, int kt) {
#pragma unroll
    for (int it = 0; it < 4; ++it) {
      const int idx = it * 512 + tid;
      const int row = idx >> 3, c = idx & 7;
      const int bo = (c * 16) ^ ((row & 7) << 4);
      gl_lds16((const char*)(A + (size_t)(m0 + row) * K + kt) + bo,
               (char*)&As[bufi][0] + (size_t)(it * 512 + wbase) * 16);
    }
  };
  auto stageB = [&](int bufi, int kt) {
#pragma unroll
    for (int it = 0; it < 4; ++it) {
      const int idx = it * 512 + tid;
      const int row = idx >> 3, c = idx & 7;
      const int bo = (c * 16) ^ ((row & 7) << 4);
      gl_lds16((const char*)(Bt + (size_t)(n0 + row) * K + kt) + bo,
               (char*)&Bs[bufi][0] + (size_t)(it * 512 + wbase) * 16);
    }
  };

  stageA(0, 0); stageB(0, 0);
  asm volatile("s_waitcnt vmcnt(0)" ::: "memory");
  __builtin_amdgcn_s_barrier();

  for (int t = 0; t < nt; ++t) {
    const int cur = t & 1;
    const bool pfch = (t + 1 < nt);
    if (pfch) stageA(cur ^ 1, (t + 1) * 64);
#pragma unroll
    for (int ks = 0; ks < 2; ++ks) {
      bf16x8 af[8], bfr[4];
#pragma unroll
      for (int mi = 0; mi < 8; ++mi) {
        const int arow = wm * 128 + mi * 16 + qr;
        const int ab = arow * 128 + ((grp * 16 + ks * 64) ^ ((arow & 7) << 4));
        af[mi] = *(const bf16x8*)((const char*)&As[cur][0] + ab);
      }
#pragma unroll
      for (int ni = 0; ni < 4; ++ni) {
        const int brow = wn * 64 + ni * 16 + qr;
        const int bb = brow * 128 + ((grp * 16 + ks * 64) ^ ((brow & 7) << 4));
        bfr[ni] = *(const bf16x8*)((const char*)&Bs[cur][0] + bb);
      }
      __builtin_amdgcn_s_setprio(1);
#pragma unroll
      for (int mi = 0; mi < 8; ++mi)
#pragma unroll
        for (int ni = 0; ni < 4; ++ni)
          acc[mi][ni] = __builtin_amdgcn_mfma_f32_16x16x32_bf16(
              af[mi], bfr[ni], acc[mi][ni], 0, 0, 0);
      __builtin_amdgcn_s_setprio(0);
      if (ks == 0 && pfch) stageB(cur ^ 1, (t + 1) * 64);
    }
    asm volatile("s_waitcnt vmcnt(0)" ::: "memory");
    __builtin_amdgcn_s_barrier();
  }

#pragma unroll
  for (int ni = 0; ni < 4; ++ni) {
    const int colg = n0 + wn * 64 + ni * 16 + qr;
    const float bv = bias[colg];
#pragma unroll
    for (int mi = 0; mi < 8; ++mi) {
      const int rowg0 = m0 + wm * 128 + mi * 16 + grp * 4;
#pragma unroll
      for (int r = 0; r < 4; ++r)
        C[(size_t)(rowg0 + r) * N + colg] = acc[mi][ni][r] + bv;
    }
  }
}

// ---------------------------------------------------------------------------
// GEMM v3 (layer GEMMs): 128x128 tile, BK=64, 4 waves, dbuf 2-phase.
// MODE 1: C=bf16 relu(acc+bias)    MODE 2: Hacc += acc (atomic if NSPLIT>1)
// MODE 3: Hacc += acc+bias (atomic, bias on split 0)
// MODE 5: QKV split: cols->q,k,Vt^T
// ---------------------------------------------------------------------------
template<int MODE, int NSPLIT>
__global__ __launch_bounds__(256) void gemm3_k(
    const bf16* __restrict__ A, const bf16* __restrict__ Bt,
    const float* __restrict__ bias, void* __restrict__ Cout,
    float* __restrict__ Hacc, bf16* __restrict__ Vt,
    int M, int N, int K)
{
  __shared__ __align__(16) bf16 As[2][128 * 64];
  __shared__ __align__(16) bf16 Bs[2][128 * 64];

  const int nwg = gridDim.x;
  const int orig = blockIdx.x;
  const int q8 = nwg >> 3, r8 = nwg & 7;
  const int xcd = orig & 7, loc = orig >> 3;
  const int wg = (xcd < r8 ? xcd * (q8 + 1) : r8 * (q8 + 1) + (xcd - r8) * q8) + loc;
  const int nrowt = M >> 7;
  const int ntiles = nrowt * (N >> 7);
  const int split = (NSPLIT > 1) ? (wg / ntiles) : 0;
  const int tile  = (NSPLIT > 1) ? (wg % ntiles) : wg;
  const int rowt = tile & (nrowt - 1);
  const int colt = tile / nrowt;
  const int m0 = rowt * 128;
  const int n0 = colt * 128;
  const int Ks = K / NSPLIT;
  const int k_begin = split * Ks;
  const int nt = Ks >> 6;

  const int tid = threadIdx.x;
  const int lane = tid & 63;
  const int wbase = tid & ~63;
  const int wid = tid >> 6;
  const int wm = wid >> 1, wn = wid & 1;
  const int qr = lane & 15, grp = lane >> 4;

  f32x4 acc[4][4];
#pragma unroll
  for (int i = 0; i < 4; ++i)
#pragma unroll
    for (int j = 0; j < 4; ++j) acc[i][j] = (f32x4){0.f, 0.f, 0.f, 0.f};

  auto stage = [&](int bufi, int kt) {
#pragma unroll
    for (int it = 0; it < 4; ++it) {
      const int idx = it * 256 + tid;
      const int row = idx >> 3, c = idx & 7;
      const int bo = (c * 16) ^ ((row & 7) << 4);
      gl_lds16((const char*)(A + (size_t)(m0 + row) * K + kt) + bo,
               (char*)&As[bufi][0] + (size_t)(it * 256 + wbase) * 16);
    }
#pragma unroll
    for (int it = 0; it < 4; ++it) {
      const int idx = it * 256 + tid;
      const int row = idx >> 3, c = idx & 7;
      const int bo = (c * 16) ^ ((row & 7) << 4);
      gl_lds16((const char*)(Bt + (size_t)(n0 + row) * K + kt) + bo,
               (char*)&Bs[bufi][0] + (size_t)(it * 256 + wbase) * 16);
    }
  };

  stage(0, k_begin);
  asm volatile("s_waitcnt vmcnt(0)" ::: "memory");
  __builtin_amdgcn_s_barrier();

  for (int t = 0; t < nt; ++t) {
    const int cur = t & 1;
    if (t + 1 < nt) stage(cur ^ 1, k_begin + (t + 1) * 64);
#pragma unroll
    for (int ks = 0; ks < 2; ++ks) {
      bf16x8 af[4], bfr[4];
#pragma unroll
      for (int mi = 0; mi < 4; ++mi) {
        const int arow = wm * 64 + mi * 16 + qr;
        const int ab = arow * 128 + ((grp * 16 + ks * 64) ^ ((arow & 7) << 4));
        af[mi] = *(const bf16x8*)((const char*)&As[cur][0] + ab);
      }
#pragma unroll
      for (int ni = 0; ni < 4; ++ni) {
        const int brow = wn * 64 + ni * 16 + qr;
        const int bb = brow * 128 + ((grp * 16 + ks * 64) ^ ((brow & 7) << 4));
        bfr[ni] = *(const bf16x8*)((const char*)&Bs[cur][0] + bb);
      }
#pragma unroll
      for (int mi = 0; mi < 4; ++mi)
#pragma unroll
        for (int ni = 0; ni < 4; ++ni)
          acc[mi][ni] = __builtin_amdgcn_mfma_f32_16x16x32_bf16(
              af[mi], bfr[ni], acc[mi][ni], 0, 0, 0);
    }
    asm volatile("s_waitcnt vmcnt(0)" ::: "memory");
    __builtin_amdgcn_s_barrier();
  }

  const int sel = (MODE == 5) ? (n0 >> 10) : 0;
#pragma unroll
  for (int ni = 0; ni < 4; ++ni) {
    const int coln = wn * 64 + ni * 16 + qr;
    const int colg = n0 + coln;
    float bv = 0.f;
    if (MODE == 1) bv = bias[colg];
    if (MODE == 3 && split == 0) bv = bias[colg];
#pragma unroll
    for (int mi = 0; mi < 4; ++mi) {
      const int rowg0 = m0 + wm * 64 + mi * 16 + grp * 4;
      if (MODE == 5 && sel == 2) {
        const int b = rowg0 >> 10, s = rowg0 & 1023;
        bf16x4 pv;
#pragma unroll
        for (int r = 0; r < 4; ++r) pv[r] = (bf16)acc[mi][ni][r];
        *(bf16x4*)(Vt + (size_t)b * 1024 * 1024 + (size_t)(colg & 1023) * 1024 + s) = pv;
      } else {
#pragma unroll
        for (int r = 0; r < 4; ++r) {
          const int rowg = rowg0 + r;
          float v = acc[mi][ni][r];
          if (MODE == 1) {
            v += bv; v = v > 0.f ? v : 0.f;
            ((bf16*)Cout)[(size_t)rowg * N + colg] = (bf16)v;
          } else if (MODE == 2) {
            if (NSPLIT > 1) atomicAdd(&Hacc[(size_t)rowg * N + colg], v);
            else            Hacc[(size_t)rowg * N + colg] += v;
          } else if (MODE == 3) {
            if (NSPLIT > 1) atomicAdd(&Hacc[(size_t)rowg * N + colg], v + bv);
            else            Hacc[(size_t)rowg * N + colg] += v + bv;
          } else if (MODE == 5) {
            bf16* cb = (bf16*)Cout + (size_t)sel * 2048 * 1024;
            cb[(size_t)rowg * 1024 + (colg & 1023)] = (bf16)v;
          }
        }
      }
    }
  }
}

// ---------------------------------------------------------------------------
// Flash attention v2: 1 wave per (b, h, 16-q-row tile); 2 kv-tiles per iter
// for unmasked bulk, masked diagonal tile last. S^T = mfma(K,Q); V from Vt.
// ---------------------------------------------------------------------------
__global__ __launch_bounds__(64) void attn_k(const bf16* __restrict__ qm,
    const bf16* __restrict__ km, const bf16* __restrict__ vt,
    bf16* __restrict__ om)
{
  const int lane = threadIdx.x;
  const int qr = lane & 15, g = lane >> 4;
  const int qt = blockIdx.x & 63;
  const int hh = (blockIdx.x >> 6) & 15;
  const int bb = blockIdx.x >> 10;
  const size_t rowb = (size_t)bb * 1024;
  const int hb = hh * 64;

  const bf16* qp = qm + (rowb + qt * 16 + qr) * 1024 + hb + g * 8;
  const bf16x8 qf0 = *(const bf16x8*)qp;
  const bf16x8 qf1 = *(const bf16x8*)(qp + 32);

  float m_run = -1e30f, l_run = 0.f;
  f32x4 oacc[4];
#pragma unroll
  for (int dt = 0; dt < 4; ++dt) oacc[dt] = (f32x4){0.f, 0.f, 0.f, 0.f};

  const int qglob = qt * 16 + qr;
  const bf16* vtb = vt + (size_t)bb * 1024 * 1024;
  const bf16* kbase = km + rowb * 1024 + hb;

  auto tile_step = [&](int kvt, bool masked) {
    const bf16* kp = kbase + (size_t)kvt * 16 * 1024 + qr * 1024 + g * 8;
    bf16x8 kf0 = *(const bf16x8*)kp;
    bf16x8 kf1 = *(const bf16x8*)(kp + 32);
    bf16x4 vf[4];
#pragma unroll
    for (int dt = 0; dt < 4; ++dt)
      vf[dt] = *(const bf16x4*)(vtb + (size_t)(hb + dt * 16 + qr) * 1024 + kvt * 16 + g * 4);
    f32x4 st = (f32x4){0.f, 0.f, 0.f, 0.f};
    st = __builtin_amdgcn_mfma_f32_16x16x32_bf16(kf0, qf0, st, 0, 0, 0);
    st = __builtin_amdgcn_mfma_f32_16x16x32_bf16(kf1, qf1, st, 0, 0, 0);
    float sc[4];
#pragma unroll
    for (int r = 0; r < 4; ++r) {
      sc[r] = st[r] * 0.125f;
      if (masked && (kvt * 16 + g * 4 + r > qglob)) sc[r] = -1e30f;
    }
    float mloc = fmaxf(fmaxf(sc[0], sc[1]), fmaxf(sc[2], sc[3]));
    mloc = fmaxf(mloc, __shfl_xor(mloc, 16));
    mloc = fmaxf(mloc, __shfl_xor(mloc, 32));
    float m_new = fmaxf(m_run, mloc);
    float alpha = __expf(m_run - m_new);
    float p[4], ps = 0.f;
#pragma unroll
    for (int r = 0; r < 4; ++r) { p[r] = __expf(sc[r] - m_new); ps += p[r]; }
    ps += __shfl_xor(ps, 16);
    ps += __shfl_xor(ps, 32);
    l_run = l_run * alpha + ps;
    m_run = m_new;
    short4v pfa;
#pragma unroll
    for (int r = 0; r < 4; ++r) pfa[r] = f2bs(p[r]);
#pragma unroll
    for (int dt = 0; dt < 4; ++dt) {
      oacc[dt] *= alpha;
      oacc[dt] = __builtin_amdgcn_mfma_f32_16x16x16bf16_1k(
          __builtin_bit_cast(short4v, vf[dt]), pfa, oacc[dt], 0, 0, 0);
    }
  };

  const int nun = qt;      // tiles 0..qt-1 fully unmasked
  int kvt = 0;
  for (; kvt + 1 < nun; kvt += 2) {
    const bf16* kpa = kbase + (size_t)kvt * 16 * 1024 + qr * 1024 + g * 8;
    const bf16* kpb = kpa + 16 * 1024;
    bf16x8 ka0 = *(const bf16x8*)kpa;
    bf16x8 ka1 = *(const bf16x8*)(kpa + 32);
    bf16x8 kb0 = *(const bf16x8*)kpb;
    bf16x8 kb1 = *(const bf16x8*)(kpb + 32);
    bf16x4 vfa[4], vfb[4];
#pragma unroll
    for (int dt = 0; dt < 4; ++dt) {
      const bf16* vp = vtb + (size_t)(hb + dt * 16 + qr) * 1024 + kvt * 16 + g * 4;
      vfa[dt] = *(const bf16x4*)vp;
      vfb[dt] = *(const bf16x4*)(vp + 16);
    }
    f32x4 sa = (f32x4){0.f, 0.f, 0.f, 0.f};
    f32x4 sb = (f32x4){0.f, 0.f, 0.f, 0.f};
    sa = __builtin_amdgcn_mfma_f32_16x16x32_bf16(ka0, qf0, sa, 0, 0, 0);
    sb = __builtin_amdgcn_mfma_f32_16x16x32_bf16(kb0, qf0, sb, 0, 0, 0);
    sa = __builtin_amdgcn_mfma_f32_16x16x32_bf16(ka1, qf1, sa, 0, 0, 0);
    sb = __builtin_amdgcn_mfma_f32_16x16x32_bf16(kb1, qf1, sb, 0, 0, 0);
    float pa[4], pb[4];
    float mloc = -1e30f;
#pragma unroll
    for (int r = 0; r < 4; ++r) {
      pa[r] = sa[r] * 0.125f; pb[r] = sb[r] * 0.125f;
      mloc = fmaxf(mloc, fmaxf(pa[r], pb[r]));
    }
    mloc = fmaxf(mloc, __shfl_xor(mloc, 16));
    mloc = fmaxf(mloc, __shfl_xor(mloc, 32));
    float m_new = fmaxf(m_run, mloc);
    float alpha = __expf(m_run - m_new);
    float ps = 0.f;
#pragma unroll
    for (int r = 0; r < 4; ++r) {
      pa[r] = __expf(pa[r] - m_new); pb[r] = __expf(pb[r] - m_new);
      ps += pa[r] + pb[r];
    }
    ps += __shfl_xor(ps, 16);
    ps += __shfl_xor(ps, 32);
    l_run = l_run * alpha + ps;
    m_run = m_new;
    short4v pfa, pfb;
#pragma unroll
    for (int r = 0; r < 4; ++r) { pfa[r] = f2bs(pa[r]); pfb[r] = f2bs(pb[r]); }
#pragma unroll
    for (int dt = 0; dt < 4; ++dt) {
      oacc[dt] *= alpha;
      oacc[dt] = __builtin_amdgcn_mfma_f32_16x16x16bf16_1k(
          __builtin_bit_cast(short4v, vfa[dt]), pfa, oacc[dt], 0, 0, 0);
      oacc[dt] = __builtin_amdgcn_mfma_f32_16x16x16bf16_1k(
          __builtin_bit_cast(short4v, vfb[dt]), pfb, oacc[dt], 0, 0, 0);
    }
  }
  for (; kvt < nun; ++kvt) tile_step(kvt, false);
  tile_step(qt, true);

  const float inv = 1.f / l_run;
  bf16* op = om + (rowb + qt * 16 + qr) * 1024 + hb;
#pragma unroll
  for (int dt = 0; dt < 4; ++dt)
#pragma unroll
    for (int r = 0; r < 4; ++r)
      op[dt * 16 + g * 4 + r] = (bf16)(oacc[dt][r] * inv);
}

// ---------------------------------------------------------------------------
extern "C" void kernel_launch(void* const* d_in, const int* in_sizes, int n_in,
                              void* d_out, int out_size, void* d_ws, size_t ws_size,
                              hipStream_t stream)
{
  (void)in_sizes; (void)n_in; (void)out_size; (void)ws_size;
  const int*   x     = (const int*)d_in[0];
  const float* emb   = (const float*)d_in[2];
  const float* Wq    = (const float*)d_in[3];
  const float* Wk    = (const float*)d_in[4];
  const float* Wv    = (const float*)d_in[5];
  const float* Wo    = (const float*)d_in[6];
  const float* ln1g  = (const float*)d_in[7];
  const float* ln1b  = (const float*)d_in[8];
  const float* ln2g  = (const float*)d_in[9];
  const float* ln2b  = (const float*)d_in[10];
  const float* W1    = (const float*)d_in[11];
  const float* b1    = (const float*)d_in[12];
  const float* W2    = (const float*)d_in[13];
  const float* b2    = (const float*)d_in[14];
  const float* lnfg  = (const float*)d_in[15];
  const float* lnfb  = (const float*)d_in[16];
  const float* projW = (const float*)d_in[17];
  const float* projb = (const float*)d_in[18];

  char* ws = (char*)d_ws;
  const size_t MB = 1u << 20;
  float* h    = (float*)(ws + 0);            // 8 MB
  bf16*  ain  = (bf16*)(ws + 8 * MB);        // 4 MB
  bf16*  qb   = (bf16*)(ws + 12 * MB);       // 4 MB
  bf16*  kb   = (bf16*)(ws + 16 * MB);       // 4 MB
  bf16*  vtb  = (bf16*)(ws + 20 * MB);       // 4 MB (V^T)
  bf16*  ob   = (bf16*)(ws + 24 * MB);       // 4 MB
  bf16*  mid  = (bf16*)(ws + 28 * MB);       // 16 MB
  bf16*  Bqkv = (bf16*)(ws + 44 * MB);       // 48 MB
  bf16*  Bo   = (bf16*)(ws + 92 * MB);       // 16 MB
  bf16*  B1t  = (bf16*)(ws + 108 * MB);      // 64 MB
  bf16*  B2t  = (bf16*)(ws + 172 * MB);      // 64 MB
  bf16*  Bprj = (bf16*)(ws + 236 * MB);      // 65.5 MB

  const long M1 = 1024 * 1024, M3 = 3 * M1, M4 = 4 * M1;

  wt_k<<<dim3(32, 16, 8),   256, 0, stream>>>(Wq, Bqkv,          1024, 1024, M1, M3);
  wt_k<<<dim3(32, 16, 8),   256, 0, stream>>>(Wk, Bqkv + M1,     1024, 1024, M1, M3);
  wt_k<<<dim3(32, 16, 8),   256, 0, stream>>>(Wv, Bqkv + 2 * M1, 1024, 1024, M1, M3);
  wt_k<<<dim3(32, 16, 8),   256, 0, stream>>>(Wo, Bo,            1024, 1024, M1, M1);
  wt_k<<<dim3(128, 16, 8),  256, 0, stream>>>(W1, B1t,           1024, 4096, M4, M4);
  wt_k<<<dim3(32, 64, 8),   256, 0, stream>>>(W2, B2t,           4096, 1024, M4, M4);
  wt_k<<<dim3(1000, 16, 1), 256, 0, stream>>>(projW, Bprj,       1024, 32000, 0, 0);

  embed_k<<<dim3(2048), 256, 0, stream>>>(x, emb, h);
  for (int i = 0; i < 8; ++i) {
    ln_k<<<dim3(2048), 256, 0, stream>>>(h, ln1g + i * 1024, ln1b + i * 1024, ain);
    gemm3_k<5,1><<<dim3(384), 256, 0, stream>>>(ain, Bqkv + i * M3, nullptr,
                                                qb, nullptr, vtb, 2048, 3072, 1024);
    attn_k<<<dim3(2048), 64, 0, stream>>>(qb, kb, vtb, ob);
    gemm3_k<2,2><<<dim3(256), 256, 0, stream>>>(ob, Bo + i * M1, nullptr,
                                                nullptr, h, nullptr, 2048, 1024, 1024);
    ln_k<<<dim3(2048), 256, 0, stream>>>(h, ln2g + i * 1024, ln2b + i * 1024, ain);
    gemm3_k<1,1><<<dim3(512), 256, 0, stream>>>(ain, B1t + i * M4, b1 + i * 4096,
                                                mid, nullptr, nullptr, 2048, 4096, 1024);
    gemm3_k<3,2><<<dim3(256), 256, 0, stream>>>(mid, B2t + i * M4, b2 + i * 1024,
                                                nullptr, h, nullptr, 2048, 1024, 4096);
  }
  ln_k<<<dim3(2048), 256, 0, stream>>>(h, lnfg, lnfb, ain);
  gemm256_k<<<dim3(1000), 512, 0, stream>>>(ain, Bprj, projb,
                                            (float*)d_out, 2048, 32000, 1024);
}

// Round 5
// 2148.763 us; speedup vs baseline: 1.6633x; 1.0097x over previous
//
#include <hip/hip_runtime.h>

typedef __bf16 bf16;
typedef __bf16 bf16x4 __attribute__((ext_vector_type(4)));
typedef __bf16 bf16x8 __attribute__((ext_vector_type(8)));
typedef float f32x4 __attribute__((ext_vector_type(4)));
typedef short short4v __attribute__((ext_vector_type(4)));

__device__ __forceinline__ short f2bs(float x) {
  bf16 hv = (bf16)x;
  return __builtin_bit_cast(short, hv);
}

__device__ __forceinline__ void gl_lds16(const void* g, void* l) {
  __builtin_amdgcn_global_load_lds(
      (const __attribute__((address_space(1))) unsigned int*)g,
      (__attribute__((address_space(3))) unsigned int*)l, 16, 0, 0);
}

// ---------------------------------------------------------------------------
// Weight transpose+convert: fp32 [K][N] -> bf16 [N][K]; 64k x 32n tile.
// ---------------------------------------------------------------------------
__global__ __launch_bounds__(256) void wt_k(const float* __restrict__ in,
    bf16* __restrict__ out, int K, int N, long in_ls, long out_ls)
{
  __shared__ float t[64][33];
  const int z = blockIdx.z;
  const float* ip = in + (size_t)z * in_ls;
  bf16* op = out + (size_t)z * out_ls;
  const int n0 = blockIdx.x * 32, k0 = blockIdx.y * 64;
  const int tid = threadIdx.x;
  const int kr = tid >> 3, nc = (tid & 7) * 4;
#pragma unroll
  for (int hh = 0; hh < 2; ++hh) {
    float4 v = *(const float4*)(ip + (size_t)(k0 + kr + hh * 32) * N + n0 + nc);
    t[kr + hh * 32][nc]     = v.x;
    t[kr + hh * 32][nc + 1] = v.y;
    t[kr + hh * 32][nc + 2] = v.z;
    t[kr + hh * 32][nc + 3] = v.w;
  }
  __syncthreads();
  const int nr = tid >> 3, kc = (tid & 7) * 8;
  bf16x8 o;
#pragma unroll
  for (int j = 0; j < 8; ++j) o[j] = (bf16)t[kc + j][nr];
  *(bf16x8*)(op + (size_t)(n0 + nr) * K + k0 + kc) = o;
}

// ---------------------------------------------------------------------------
// Embedding: h[m][d] = emb[x[m]][d]*32 + PE(s,d)
// ---------------------------------------------------------------------------
__global__ __launch_bounds__(256) void embed_k(const int* __restrict__ x,
    const float* __restrict__ emb, float* __restrict__ h)
{
  const int m = blockIdx.x, t = threadIdx.x;
  const int s = m & 1023;
  const int tok = x[m];
  const int d0 = t * 4;
  float4 e = *(const float4*)(emb + (size_t)tok * 1024 + d0);
  const float* ep = &e.x;
  float r[4];
#pragma unroll
  for (int j = 0; j < 4; ++j) {
    int d = d0 + j;
    float freq = expf((float)(d & ~1) * (-9.2103403719761836f / 1024.f));
    float ang = (float)s * freq;
    float pe = (d & 1) ? cosf(ang) : sinf(ang);
    r[j] = ep[j] * 32.f + pe;
  }
  *(float4*)(h + (size_t)m * 1024 + d0) = make_float4(r[0], r[1], r[2], r[3]);
}

// ---------------------------------------------------------------------------
// LayerNorm (fp32 in, bf16 out), one block per row of 1024
// ---------------------------------------------------------------------------
__global__ __launch_bounds__(256) void ln_k(const float* __restrict__ h,
    const float* __restrict__ g, const float* __restrict__ b,
    bf16* __restrict__ out)
{
  const int row = blockIdx.x, t = threadIdx.x;
  const float* hr = h + (size_t)row * 1024;
  float4 x = *(const float4*)(hr + t * 4);
  float s  = x.x + x.y + x.z + x.w;
  float ss = x.x * x.x + x.y * x.y + x.z * x.z + x.w * x.w;
#pragma unroll
  for (int off = 32; off >= 1; off >>= 1) {
    s  += __shfl_down(s, off);
    ss += __shfl_down(ss, off);
  }
  __shared__ float sb[4], ssb[4];
  if ((t & 63) == 0) { sb[t >> 6] = s; ssb[t >> 6] = ss; }
  __syncthreads();
  s  = sb[0] + sb[1] + sb[2] + sb[3];
  ss = ssb[0] + ssb[1] + ssb[2] + ssb[3];
  const float mean = s * (1.f / 1024.f);
  const float var  = ss * (1.f / 1024.f) - mean * mean;
  const float rstd = rsqrtf(var + 1e-5f);
  const float* xp = &x.x;
#pragma unroll
  for (int j = 0; j < 4; ++j) {
    int d = t * 4 + j;
    out[(size_t)row * 1024 + d] = (bf16)((xp[j] - mean) * rstd * g[d] + b[d]);
  }
}

// ---------------------------------------------------------------------------
// GEMM 256x256 (proj): C(f32) = A(bf16 [M][K]) * Bt(bf16 [N][K])^T + bias
// BK=64, 16 waves (4Mx4N), per-wave 64x64 out, dbuf LDS 128KB.
// Counted-vmcnt pipeline: {stage(t+1); vmcnt(4); barrier; compute(t); barrier}
// -> tile t+1's 4 loads/thread stay in flight across the whole MFMA phase.
// Operand-swapped MFMA: D rows<->n, cols<->m => coalesced float4 C stores.
// ---------------------------------------------------------------------------
__global__ __launch_bounds__(1024) void gemm256_k(
    const bf16* __restrict__ A, const bf16* __restrict__ Bt,
    const float* __restrict__ bias, float* __restrict__ C,
    int M, int N, int K)
{
  __shared__ __align__(16) bf16 As[2][256 * 64];
  __shared__ __align__(16) bf16 Bs[2][256 * 64];

  const int nwg = gridDim.x;
  const int orig = blockIdx.x;
  const int q8 = nwg >> 3, r8 = nwg & 7;
  const int xcd = orig & 7, loc = orig >> 3;
  const int wg = (xcd < r8 ? xcd * (q8 + 1) : r8 * (q8 + 1) + (xcd - r8) * q8) + loc;
  const int nrowt = M >> 8;
  const int rowt = wg & (nrowt - 1);
  const int colt = wg / nrowt;
  const int m0 = rowt * 256;
  const int n0 = colt * 256;
  const int nt = K >> 6;

  const int tid = threadIdx.x;
  const int lane = tid & 63;
  const int wbase = tid & ~63;
  const int wid = tid >> 6;
  const int wm = wid >> 2, wn = wid & 3;
  const int qr = lane & 15, grp = lane >> 4;

  f32x4 acc[4][4];
#pragma unroll
  for (int i = 0; i < 4; ++i)
#pragma unroll
    for (int j = 0; j < 4; ++j) acc[i][j] = (f32x4){0.f, 0.f, 0.f, 0.f};

  auto stage = [&](int bufi, int kt) {
#pragma unroll
    for (int it = 0; it < 2; ++it) {
      const int idx = it * 1024 + tid;
      const int row = idx >> 3, c = idx & 7;
      const int bo = (c * 16) ^ ((row & 7) << 4);
      gl_lds16((const char*)(A + (size_t)(m0 + row) * K + kt) + bo,
               (char*)&As[bufi][0] + (size_t)(it * 1024 + wbase) * 16);
    }
#pragma unroll
    for (int it = 0; it < 2; ++it) {
      const int idx = it * 1024 + tid;
      const int row = idx >> 3, c = idx & 7;
      const int bo = (c * 16) ^ ((row & 7) << 4);
      gl_lds16((const char*)(Bt + (size_t)(n0 + row) * K + kt) + bo,
               (char*)&Bs[bufi][0] + (size_t)(it * 1024 + wbase) * 16);
    }
  };

  stage(0, 0);
  for (int t = 0; t < nt; ++t) {
    const int cur = t & 1;
    if (t + 1 < nt) {
      stage(cur ^ 1, (t + 1) * 64);
      asm volatile("s_waitcnt vmcnt(4)" ::: "memory");
    } else {
      asm volatile("s_waitcnt vmcnt(0)" ::: "memory");
    }
    __builtin_amdgcn_s_barrier();
    asm volatile("" ::: "memory");
#pragma unroll
    for (int ks = 0; ks < 2; ++ks) {
      bf16x8 af[4], bfr[4];
#pragma unroll
      for (int mi = 0; mi < 4; ++mi) {
        const int arow = wm * 64 + mi * 16 + qr;
        const int ab = arow * 128 + ((grp * 16 + ks * 64) ^ ((arow & 7) << 4));
        af[mi] = *(const bf16x8*)((const char*)&As[cur][0] + ab);
      }
#pragma unroll
      for (int ni = 0; ni < 4; ++ni) {
        const int brow = wn * 64 + ni * 16 + qr;
        const int bb = brow * 128 + ((grp * 16 + ks * 64) ^ ((brow & 7) << 4));
        bfr[ni] = *(const bf16x8*)((const char*)&Bs[cur][0] + bb);
      }
      __builtin_amdgcn_s_setprio(1);
#pragma unroll
      for (int mi = 0; mi < 4; ++mi)
#pragma unroll
        for (int ni = 0; ni < 4; ++ni)
          acc[mi][ni] = __builtin_amdgcn_mfma_f32_16x16x32_bf16(
              bfr[ni], af[mi], acc[mi][ni], 0, 0, 0);  // swapped: rows<->n
      __builtin_amdgcn_s_setprio(0);
    }
    __builtin_amdgcn_s_barrier();
    asm volatile("" ::: "memory");
  }

  // epilogue: lane holds C[m = ...+qr][n = ...+grp*4 + r] -> float4 stores
#pragma unroll
  for (int mi = 0; mi < 4; ++mi) {
    const int rowg = m0 + wm * 64 + mi * 16 + qr;
#pragma unroll
    for (int ni = 0; ni < 4; ++ni) {
      const int colg = n0 + wn * 64 + ni * 16 + grp * 4;
      float4 bv = *(const float4*)(bias + colg);
      float4 o;
      o.x = acc[mi][ni][0] + bv.x;
      o.y = acc[mi][ni][1] + bv.y;
      o.z = acc[mi][ni][2] + bv.z;
      o.w = acc[mi][ni][3] + bv.w;
      *(float4*)(C + (size_t)rowg * N + colg) = o;
    }
  }
}

// ---------------------------------------------------------------------------
// GEMM v4 (layer GEMMs): 128x128 tile, BK=64, 4 waves, dbuf, counted-vmcnt
// pipeline (same schedule as gemm256_k, N=8 loads/thread/tile).
// MODE 1: C=bf16 relu(acc+bias)    MODE 2: Hacc += acc (atomic if NSPLIT>1)
// MODE 3: Hacc += acc+bias (atomic, bias on split 0)
// MODE 5: QKV split: cols->q,k,Vt^T
// ---------------------------------------------------------------------------
template<int MODE, int NSPLIT>
__global__ __launch_bounds__(256) void gemm3_k(
    const bf16* __restrict__ A, const bf16* __restrict__ Bt,
    const float* __restrict__ bias, void* __restrict__ Cout,
    float* __restrict__ Hacc, bf16* __restrict__ Vt,
    int M, int N, int K)
{
  __shared__ __align__(16) bf16 As[2][128 * 64];
  __shared__ __align__(16) bf16 Bs[2][128 * 64];

  const int nwg = gridDim.x;
  const int orig = blockIdx.x;
  const int q8 = nwg >> 3, r8 = nwg & 7;
  const int xcd = orig & 7, loc = orig >> 3;
  const int wg = (xcd < r8 ? xcd * (q8 + 1) : r8 * (q8 + 1) + (xcd - r8) * q8) + loc;
  const int nrowt = M >> 7;
  const int ntiles = nrowt * (N >> 7);
  const int split = (NSPLIT > 1) ? (wg / ntiles) : 0;
  const int tile  = (NSPLIT > 1) ? (wg % ntiles) : wg;
  const int rowt = tile & (nrowt - 1);
  const int colt = tile / nrowt;
  const int m0 = rowt * 128;
  const int n0 = colt * 128;
  const int Ks = K / NSPLIT;
  const int k_begin = split * Ks;
  const int nt = Ks >> 6;

  const int tid = threadIdx.x;
  const int lane = tid & 63;
  const int wbase = tid & ~63;
  const int wid = tid >> 6;
  const int wm = wid >> 1, wn = wid & 1;
  const int qr = lane & 15, grp = lane >> 4;

  f32x4 acc[4][4];
#pragma unroll
  for (int i = 0; i < 4; ++i)
#pragma unroll
    for (int j = 0; j < 4; ++j) acc[i][j] = (f32x4){0.f, 0.f, 0.f, 0.f};

  auto stage = [&](int bufi, int kt) {
#pragma unroll
    for (int it = 0; it < 4; ++it) {
      const int idx = it * 256 + tid;
      const int row = idx >> 3, c = idx & 7;
      const int bo = (c * 16) ^ ((row & 7) << 4);
      gl_lds16((const char*)(A + (size_t)(m0 + row) * K + kt) + bo,
               (char*)&As[bufi][0] + (size_t)(it * 256 + wbase) * 16);
    }
#pragma unroll
    for (int it = 0; it < 4; ++it) {
      const int idx = it * 256 + tid;
      const int row = idx >> 3, c = idx & 7;
      const int bo = (c * 16) ^ ((row & 7) << 4);
      gl_lds16((const char*)(Bt + (size_t)(n0 + row) * K + kt) + bo,
               (char*)&Bs[bufi][0] + (size_t)(it * 256 + wbase) * 16);
    }
  };

  stage(0, k_begin);
  for (int t = 0; t < nt; ++t) {
    const int cur = t & 1;
    if (t + 1 < nt) {
      stage(cur ^ 1, k_begin + (t + 1) * 64);
      asm volatile("s_waitcnt vmcnt(8)" ::: "memory");
    } else {
      asm volatile("s_waitcnt vmcnt(0)" ::: "memory");
    }
    __builtin_amdgcn_s_barrier();
    asm volatile("" ::: "memory");
#pragma unroll
    for (int ks = 0; ks < 2; ++ks) {
      bf16x8 af[4], bfr[4];
#pragma unroll
      for (int mi = 0; mi < 4; ++mi) {
        const int arow = wm * 64 + mi * 16 + qr;
        const int ab = arow * 128 + ((grp * 16 + ks * 64) ^ ((arow & 7) << 4));
        af[mi] = *(const bf16x8*)((const char*)&As[cur][0] + ab);
      }
#pragma unroll
      for (int ni = 0; ni < 4; ++ni) {
        const int brow = wn * 64 + ni * 16 + qr;
        const int bb = brow * 128 + ((grp * 16 + ks * 64) ^ ((brow & 7) << 4));
        bfr[ni] = *(const bf16x8*)((const char*)&Bs[cur][0] + bb);
      }
      __builtin_amdgcn_s_setprio(1);
#pragma unroll
      for (int mi = 0; mi < 4; ++mi)
#pragma unroll
        for (int ni = 0; ni < 4; ++ni)
          acc[mi][ni] = __builtin_amdgcn_mfma_f32_16x16x32_bf16(
              af[mi], bfr[ni], acc[mi][ni], 0, 0, 0);
      __builtin_amdgcn_s_setprio(0);
    }
    __builtin_amdgcn_s_barrier();
    asm volatile("" ::: "memory");
  }

  const int sel = (MODE == 5) ? (n0 >> 10) : 0;
#pragma unroll
  for (int ni = 0; ni < 4; ++ni) {
    const int coln = wn * 64 + ni * 16 + qr;
    const int colg = n0 + coln;
    float bv = 0.f;
    if (MODE == 1) bv = bias[colg];
    if (MODE == 3 && split == 0) bv = bias[colg];
#pragma unroll
    for (int mi = 0; mi < 4; ++mi) {
      const int rowg0 = m0 + wm * 64 + mi * 16 + grp * 4;
      if (MODE == 5 && sel == 2) {
        const int b = rowg0 >> 10, s = rowg0 & 1023;
        bf16x4 pv;
#pragma unroll
        for (int r = 0; r < 4; ++r) pv[r] = (bf16)acc[mi][ni][r];
        *(bf16x4*)(Vt + (size_t)b * 1024 * 1024 + (size_t)(colg & 1023) * 1024 + s) = pv;
      } else {
#pragma unroll
        for (int r = 0; r < 4; ++r) {
          const int rowg = rowg0 + r;
          float v = acc[mi][ni][r];
          if (MODE == 1) {
            v += bv; v = v > 0.f ? v : 0.f;
            ((bf16*)Cout)[(size_t)rowg * N + colg] = (bf16)v;
          } else if (MODE == 2) {
            if (NSPLIT > 1) atomicAdd(&Hacc[(size_t)rowg * N + colg], v);
            else            Hacc[(size_t)rowg * N + colg] += v;
          } else if (MODE == 3) {
            if (NSPLIT > 1) atomicAdd(&Hacc[(size_t)rowg * N + colg], v + bv);
            else            Hacc[(size_t)rowg * N + colg] += v + bv;
          } else if (MODE == 5) {
            bf16* cb = (bf16*)Cout + (size_t)sel * 2048 * 1024;
            cb[(size_t)rowg * 1024 + (colg & 1023)] = (bf16)v;
          }
        }
      }
    }
  }
}

// ---------------------------------------------------------------------------
// Flash attention (unchanged from round 4): 1 wave per (b, h, 16-q-row tile);
// 2 kv-tiles per iter for unmasked bulk, masked diagonal tile last.
// ---------------------------------------------------------------------------
__global__ __launch_bounds__(64) void attn_k(const bf16* __restrict__ qm,
    const bf16* __restrict__ km, const bf16* __restrict__ vt,
    bf16* __restrict__ om)
{
  const int lane = threadIdx.x;
  const int qr = lane & 15, g = lane >> 4;
  const int qt = blockIdx.x & 63;
  const int hh = (blockIdx.x >> 6) & 15;
  const int bb = blockIdx.x >> 10;
  const size_t rowb = (size_t)bb * 1024;
  const int hb = hh * 64;

  const bf16* qp = qm + (rowb + qt * 16 + qr) * 1024 + hb + g * 8;
  const bf16x8 qf0 = *(const bf16x8*)qp;
  const bf16x8 qf1 = *(const bf16x8*)(qp + 32);

  float m_run = -1e30f, l_run = 0.f;
  f32x4 oacc[4];
#pragma unroll
  for (int dt = 0; dt < 4; ++dt) oacc[dt] = (f32x4){0.f, 0.f, 0.f, 0.f};

  const int qglob = qt * 16 + qr;
  const bf16* vtb = vt + (size_t)bb * 1024 * 1024;
  const bf16* kbase = km + rowb * 1024 + hb;

  auto tile_step = [&](int kvt, bool masked) {
    const bf16* kp = kbase + (size_t)kvt * 16 * 1024 + qr * 1024 + g * 8;
    bf16x8 kf0 = *(const bf16x8*)kp;
    bf16x8 kf1 = *(const bf16x8*)(kp + 32);
    bf16x4 vf[4];
#pragma unroll
    for (int dt = 0; dt < 4; ++dt)
      vf[dt] = *(const bf16x4*)(vtb + (size_t)(hb + dt * 16 + qr) * 1024 + kvt * 16 + g * 4);
    f32x4 st = (f32x4){0.f, 0.f, 0.f, 0.f};
    st = __builtin_amdgcn_mfma_f32_16x16x32_bf16(kf0, qf0, st, 0, 0, 0);
    st = __builtin_amdgcn_mfma_f32_16x16x32_bf16(kf1, qf1, st, 0, 0, 0);
    float sc[4];
#pragma unroll
    for (int r = 0; r < 4; ++r) {
      sc[r] = st[r] * 0.125f;
      if (masked && (kvt * 16 + g * 4 + r > qglob)) sc[r] = -1e30f;
    }
    float mloc = fmaxf(fmaxf(sc[0], sc[1]), fmaxf(sc[2], sc[3]));
    mloc = fmaxf(mloc, __shfl_xor(mloc, 16));
    mloc = fmaxf(mloc, __shfl_xor(mloc, 32));
    float m_new = fmaxf(m_run, mloc);
    float alpha = __expf(m_run - m_new);
    float p[4], ps = 0.f;
#pragma unroll
    for (int r = 0; r < 4; ++r) { p[r] = __expf(sc[r] - m_new); ps += p[r]; }
    ps += __shfl_xor(ps, 16);
    ps += __shfl_xor(ps, 32);
    l_run = l_run * alpha + ps;
    m_run = m_new;
    short4v pfa;
#pragma unroll
    for (int r = 0; r < 4; ++r) pfa[r] = f2bs(p[r]);
#pragma unroll
    for (int dt = 0; dt < 4; ++dt) {
      oacc[dt] *= alpha;
      oacc[dt] = __builtin_amdgcn_mfma_f32_16x16x16bf16_1k(
          __builtin_bit_cast(short4v, vf[dt]), pfa, oacc[dt], 0, 0, 0);
    }
  };

  const int nun = qt;      // tiles 0..qt-1 fully unmasked
  int kvt = 0;
  for (; kvt + 1 < nun; kvt += 2) {
    const bf16* kpa = kbase + (size_t)kvt * 16 * 1024 + qr * 1024 + g * 8;
    const bf16* kpb = kpa + 16 * 1024;
    bf16x8 ka0 = *(const bf16x8*)kpa;
    bf16x8 ka1 = *(const bf16x8*)(kpa + 32);
    bf16x8 kb0 = *(const bf16x8*)kpb;
    bf16x8 kb1 = *(const bf16x8*)(kpb + 32);
    bf16x4 vfa[4], vfb[4];
#pragma unroll
    for (int dt = 0; dt < 4; ++dt) {
      const bf16* vp = vtb + (size_t)(hb + dt * 16 + qr) * 1024 + kvt * 16 + g * 4;
      vfa[dt] = *(const bf16x4*)vp;
      vfb[dt] = *(const bf16x4*)(vp + 16);
    }
    f32x4 sa = (f32x4){0.f, 0.f, 0.f, 0.f};
    f32x4 sb = (f32x4){0.f, 0.f, 0.f, 0.f};
    sa = __builtin_amdgcn_mfma_f32_16x16x32_bf16(ka0, qf0, sa, 0, 0, 0);
    sb = __builtin_amdgcn_mfma_f32_16x16x32_bf16(kb0, qf0, sb, 0, 0, 0);
    sa = __builtin_amdgcn_mfma_f32_16x16x32_bf16(ka1, qf1, sa, 0, 0, 0);
    sb = __builtin_amdgcn_mfma_f32_16x16x32_bf16(kb1, qf1, sb, 0, 0, 0);
    float pa[4], pb[4];
    float mloc = -1e30f;
#pragma unroll
    for (int r = 0; r < 4; ++r) {
      pa[r] = sa[r] * 0.125f; pb[r] = sb[r] * 0.125f;
      mloc = fmaxf(mloc, fmaxf(pa[r], pb[r]));
    }
    mloc = fmaxf(mloc, __shfl_xor(mloc, 16));
    mloc = fmaxf(mloc, __shfl_xor(mloc, 32));
    float m_new = fmaxf(m_run, mloc);
    float alpha = __expf(m_run - m_new);
    float ps = 0.f;
#pragma unroll
    for (int r = 0; r < 4; ++r) {
      pa[r] = __expf(pa[r] - m_new); pb[r] = __expf(pb[r] - m_new);
      ps += pa[r] + pb[r];
    }
    ps += __shfl_xor(ps, 16);
    ps += __shfl_xor(ps, 32);
    l_run = l_run * alpha + ps;
    m_run = m_new;
    short4v pfa, pfb;
#pragma unroll
    for (int r = 0; r < 4; ++r) { pfa[r] = f2bs(pa[r]); pfb[r] = f2bs(pb[r]); }
#pragma unroll
    for (int dt = 0; dt < 4; ++dt) {
      oacc[dt] *= alpha;
      oacc[dt] = __builtin_amdgcn_mfma_f32_16x16x16bf16_1k(
          __builtin_bit_cast(short4v, vfa[dt]), pfa, oacc[dt], 0, 0, 0);
      oacc[dt] = __builtin_amdgcn_mfma_f32_16x16x16bf16_1k(
          __builtin_bit_cast(short4v, vfb[dt]), pfb, oacc[dt], 0, 0, 0);
    }
  }
  for (; kvt < nun; ++kvt) tile_step(kvt, false);
  tile_step(qt, true);

  const float inv = 1.f / l_run;
  bf16* op = om + (rowb + qt * 16 + qr) * 1024 + hb;
#pragma unroll
  for (int dt = 0; dt < 4; ++dt)
#pragma unroll
    for (int r = 0; r < 4; ++r)
      op[dt * 16 + g * 4 + r] = (bf16)(oacc[dt][r] * inv);
}

// ---------------------------------------------------------------------------
extern "C" void kernel_launch(void* const* d_in, const int* in_sizes, int n_in,
                              void* d_out, int out_size, void* d_ws, size_t ws_size,
                              hipStream_t stream)
{
  (void)in_sizes; (void)n_in; (void)out_size; (void)ws_size;
  const int*   x     = (const int*)d_in[0];
  const float* emb   = (const float*)d_in[2];
  const float* Wq    = (const float*)d_in[3];
  const float* Wk    = (const float*)d_in[4];
  const float* Wv    = (const float*)d_in[5];
  const float* Wo    = (const float*)d_in[6];
  const float* ln1g  = (const float*)d_in[7];
  const float* ln1b  = (const float*)d_in[8];
  const float* ln2g  = (const float*)d_in[9];
  const float* ln2b  = (const float*)d_in[10];
  const float* W1    = (const float*)d_in[11];
  const float* b1    = (const float*)d_in[12];
  const float* W2    = (const float*)d_in[13];
  const float* b2    = (const float*)d_in[14];
  const float* lnfg  = (const float*)d_in[15];
  const float* lnfb  = (const float*)d_in[16];
  const float* projW = (const float*)d_in[17];
  const float* projb = (const float*)d_in[18];

  char* ws = (char*)d_ws;
  const size_t MB = 1u << 20;
  float* h    = (float*)(ws + 0);            // 8 MB
  bf16*  ain  = (bf16*)(ws + 8 * MB);        // 4 MB
  bf16*  qb   = (bf16*)(ws + 12 * MB);       // 4 MB
  bf16*  kb   = (bf16*)(ws + 16 * MB);       // 4 MB
  bf16*  vtb  = (bf16*)(ws + 20 * MB);       // 4 MB (V^T)
  bf16*  ob   = (bf16*)(ws + 24 * MB);       // 4 MB
  bf16*  mid  = (bf16*)(ws + 28 * MB);       // 16 MB
  bf16*  Bqkv = (bf16*)(ws + 44 * MB);       // 48 MB
  bf16*  Bo   = (bf16*)(ws + 92 * MB);       // 16 MB
  bf16*  B1t  = (bf16*)(ws + 108 * MB);      // 64 MB
  bf16*  B2t  = (bf16*)(ws + 172 * MB);      // 64 MB
  bf16*  Bprj = (bf16*)(ws + 236 * MB);      // 65.5 MB

  const long M1 = 1024 * 1024, M3 = 3 * M1, M4 = 4 * M1;

  wt_k<<<dim3(32, 16, 8),   256, 0, stream>>>(Wq, Bqkv,          1024, 1024, M1, M3);
  wt_k<<<dim3(32, 16, 8),   256, 0, stream>>>(Wk, Bqkv + M1,     1024, 1024, M1, M3);
  wt_k<<<dim3(32, 16, 8),   256, 0, stream>>>(Wv, Bqkv + 2 * M1, 1024, 1024, M1, M3);
  wt_k<<<dim3(32, 16, 8),   256, 0, stream>>>(Wo, Bo,            1024, 1024, M1, M1);
  wt_k<<<dim3(128, 16, 8),  256, 0, stream>>>(W1, B1t,           1024, 4096, M4, M4);
  wt_k<<<dim3(32, 64, 8),   256, 0, stream>>>(W2, B2t,           4096, 1024, M4, M4);
  wt_k<<<dim3(1000, 16, 1), 256, 0, stream>>>(projW, Bprj,       1024, 32000, 0, 0);

  embed_k<<<dim3(2048), 256, 0, stream>>>(x, emb, h);
  for (int i = 0; i < 8; ++i) {
    ln_k<<<dim3(2048), 256, 0, stream>>>(h, ln1g + i * 1024, ln1b + i * 1024, ain);
    gemm3_k<5,1><<<dim3(384), 256, 0, stream>>>(ain, Bqkv + i * M3, nullptr,
                                                qb, nullptr, vtb, 2048, 3072, 1024);
    attn_k<<<dim3(2048), 64, 0, stream>>>(qb, kb, vtb, ob);
    gemm3_k<2,2><<<dim3(256), 256, 0, stream>>>(ob, Bo + i * M1, nullptr,
                                                nullptr, h, nullptr, 2048, 1024, 1024);
    ln_k<<<dim3(2048), 256, 0, stream>>>(h, ln2g + i * 1024, ln2b + i * 1024, ain);
    gemm3_k<1,1><<<dim3(512), 256, 0, stream>>>(ain, B1t + i * M4, b1 + i * 4096,
                                                mid, nullptr, nullptr, 2048, 4096, 1024);
    gemm3_k<3,2><<<dim3(256), 256, 0, stream>>>(mid, B2t + i * M4, b2 + i * 1024,
                                                nullptr, h, nullptr, 2048, 1024, 4096);
  }
  ln_k<<<dim3(2048), 256, 0, stream>>>(h, lnfg, lnfb, ain);
  gemm256_k<<<dim3(1000), 1024, 0, stream>>>(ain, Bprj, projb,
                                             (float*)d_out, 2048, 32000, 1024);
}